// Round 11
// baseline (249.576 us; speedup 1.0000x reference)
//
#include <hip/hip_runtime.h>

typedef unsigned short u16;
typedef unsigned int u32;
typedef __attribute__((ext_vector_type(4))) int i32x4;
typedef __attribute__((ext_vector_type(4))) float f32x4;
typedef __attribute__((ext_vector_type(4))) u16 u16x4;
typedef __attribute__((ext_vector_type(8))) u16 u16x8;

#define PTOT 131072   // 128 images * 32*32 pixels
#define NREP 16       // stat accumulator replicas (atomic de-contention)

// ---------- helpers ----------
static __device__ __forceinline__ int qi8(float v) {  // round-half-even, clip +-127
  int q = (int)rintf(v * 128.f);
  return max(-127, min(127, q));
}
static __device__ __forceinline__ u16 bf_rne(float v) { // round-nearest-even bf16
  u32 u = __float_as_uint(v);
  u += 0x7fffu + ((u >> 16) & 1u);
  return (u16)(u >> 16);
}
static __device__ __forceinline__ float bf2f(u16 v) {
  return __uint_as_float((u32)v << 16);
}

// ---------- weight quantize + i8 MFMA fragment packing (row-linear K) ----------
// packed: [NCH][NF][64 lanes][16 B]; co = nf*16+(lane&15),
// k = c*64 + (lane>>4)*16 + j over row-linear K: r = k/KROWP, kk = k%KROWP;
// kk < 3*CIr -> (kh=r, kw=kk/CIr, ci=kk%CIr); else zero (row tail pad).
struct WPtrs { const float* p[7]; };

__global__ void wpack_kernel(WPtrs wp, char* __restrict__ o) {
  // {byte_off, CIr, KROWP, KH, Co}   (len = NCH*NF*1024)
  static const int S[7][5] = {
      {0,      192, 192, 1, 64},   // b1   NCH=3 NF=4  12288
      {12288,  192, 192, 1, 96},   // b2a  NCH=3 NF=6  18432
      {30720,  96,  320, 3, 128},  // b2b  NCH=15 NF=8 122880
      {153600, 192, 192, 1, 16},   // b3a  NCH=3 NF=1  3072
      {156672, 16,  64,  3, 32},   // b3b  NCH=3 NF=2  6144
      {162816, 32,  128, 3, 32},   // b3c  NCH=6 NF=2  12288
      {175104, 192, 192, 1, 32},   // b4   NCH=3 NF=2  6144
  };
  int idx = blockIdx.x * 256 + threadIdx.x;
  if (idx >= 181248) return;
  int s = 0;
#pragma unroll
  for (int i = 1; i < 7; ++i)
    if (idx >= S[i][0]) s = i;
  int local = idx - S[s][0];
  int CIr = S[s][1], KROWP = S[s][2], KH = S[s][3], Co = S[s][4];
  int j = local & 15, lane = (local >> 4) & 63, f = local >> 10;
  int NF = Co >> 4;
  int c = f / NF, nf = f - c * NF;
  int co = nf * 16 + (lane & 15);
  int k = c * 64 + ((lane >> 4) << 4) + j;
  int r = k / KROWP, kk = k - r * KROWP;
  char val = 0;
  if (kk < 3 * CIr || KH == 1) {
    int kw = (KH == 1) ? 0 : (kk / CIr);
    int ci = (KH == 1) ? kk : (kk - kw * CIr);
    val = (char)qi8(wp.p[s][(((size_t)co * CIr + ci) * KH + r) * KH + kw]);
  }
  o[idx] = val;
}

// ---------- quantize x: NCHW f32 -> NHWC int8 ----------
__global__ __launch_bounds__(256) void quantx_kernel(const float* __restrict__ x,
                                                     char* __restrict__ xq) {
  __shared__ __align__(16) char tile[64][80];
  int n = blockIdx.z, hwb = blockIdx.x * 64, cb = blockIdx.y * 64;
  int lane = threadIdx.x & 63, sub = threadIdx.x >> 6;
#pragma unroll
  for (int i = 0; i < 16; ++i) {
    int c = sub + i * 4;
    float v = x[(((size_t)n * 192 + cb + c) << 10) + hwb + lane];
    tile[lane][c] = (char)qi8(v);
  }
  __syncthreads();
  int t = threadIdx.x, px = t >> 2, c16 = t & 3;
  uint4 v = *(const uint4*)&tile[px][c16 * 16];
  *(uint4*)&xq[(((size_t)n << 10) + hwb + px) * 192 + cb + c16 * 16] = v;
}

// ---------- maxpool 3x3 s1 p1 on int8 NHWC ----------
__global__ __launch_bounds__(256) void pool_kernel(const char* __restrict__ xq,
                                                   char* __restrict__ xpq) {
  int idx = blockIdx.x * 256 + threadIdx.x;
  int c16 = idx % 12;
  int p = idx / 12;
  int n = p >> 10, hw = p & 1023, h = hw >> 5, w = hw & 31;
  int m[16];
#pragma unroll
  for (int j = 0; j < 16; ++j) m[j] = -127;
  for (int dh = -1; dh <= 1; ++dh) {
    int hh = h + dh; if (hh < 0 || hh > 31) continue;
    for (int dw = -1; dw <= 1; ++dw) {
      int ww = w + dw; if (ww < 0 || ww > 31) continue;
      uint4 v = *(const uint4*)&xq[((((size_t)n << 5) + hh) * 32 + ww) * 192 + c16 * 16];
      const char* bb = reinterpret_cast<const char*>(&v);
#pragma unroll
      for (int t = 0; t < 16; ++t) {
        int b = (int)bb[t];
        m[t] = b > m[t] ? b : m[t];
      }
    }
  }
  uint4 o;
  char* ob = reinterpret_cast<char*>(&o);
#pragma unroll
  for (int t = 0; t < 16; ++t) ob[t] = (char)m[t];
  *(uint4*)&xpq[(size_t)p * 192 + c16 * 16] = o;
}

// ---------- zero the 1-px borders of padded q buffers ----------
__global__ __launch_bounds__(256) void border_kernel(char* __restrict__ q2a,
                                                     char* __restrict__ q3a,
                                                     char* __restrict__ q3b) {
  int img = blockIdx.x, buf = blockIdx.y;
  char* base; int C;
  if (buf == 0) { base = q2a; C = 96; }
  else if (buf == 1) { base = q3a; C = 16; }
  else { base = q3b; C = 32; }
  char* ib = base + (size_t)img * 34 * 34 * C;
  int nch = C >> 4;
  uint4 z = {0, 0, 0, 0};
  for (int idx = threadIdx.x; idx < 132 * nch; idx += 256) {
    int b = idx / nch, cc = idx - b * nch;
    int h, w;
    if (b < 34) { h = 0; w = b; }
    else if (b < 68) { h = 33; w = b - 34; }
    else { int s = b - 68; h = 1 + (s >> 1); w = (s & 1) ? 33 : 0; }
    *(uint4*)(ib + ((h * 34 + w) * C + cc * 16)) = z;
  }
}

// ---------- shared conv epilogue: yh write + stats reduce + atomics ----------
template <int NFW, int MF>
static __device__ __forceinline__ void conv_epilogue(
    i32x4 (&acc)[MF][NFW], int lane, int wave, int mbase,
    u16* __restrict__ yh, double* __restrict__ stb, int ststride) {
  constexpr int COB = NFW * 16;
  float yv[MF][NFW][4];
#pragma unroll
  for (int mf = 0; mf < MF; ++mf)
#pragma unroll
    for (int nf = 0; nf < NFW; ++nf) {
      int col = nf * 16 + (lane & 15);
      int pix = mbase + mf * 16 + ((lane >> 4) << 2);
      u16x4 o;
#pragma unroll
      for (int r = 0; r < 4; ++r) {
        float v = (float)acc[mf][nf][r] * 6.103515625e-05f;  // 2^-14 (exact)
        yv[mf][nf][r] = v;
        o[r] = bf_rne(v);
      }
      *(u16x4*)&yh[(size_t)col * PTOT + pix] = o;
    }

  float s1[NFW], s2[NFW];
#pragma unroll
  for (int nf = 0; nf < NFW; ++nf) { s1[nf] = 0.f; s2[nf] = 0.f; }
#pragma unroll
  for (int mf = 0; mf < MF; ++mf)
#pragma unroll
    for (int nf = 0; nf < NFW; ++nf)
#pragma unroll
      for (int r = 0; r < 4; ++r) {
        float v = yv[mf][nf][r];
        s1[nf] += v;
        s2[nf] += v * v;
      }
#pragma unroll
  for (int m = 16; m <= 32; m <<= 1)
#pragma unroll
    for (int nf = 0; nf < NFW; ++nf) {
      s1[nf] += __shfl_xor(s1[nf], m);
      s2[nf] += __shfl_xor(s2[nf], m);
    }
  __shared__ float red[4][NFW][16][2];
  if (lane < 16)
#pragma unroll
    for (int nf = 0; nf < NFW; ++nf) {
      red[wave][nf][lane][0] = s1[nf];
      red[wave][nf][lane][1] = s2[nf];
    }
  __syncthreads();
  const int t = threadIdx.x;
  if (t < COB) {
    int nf = t >> 4, l = t & 15;
    float a = red[0][nf][l][0] + red[1][nf][l][0] + red[2][nf][l][0] + red[3][nf][l][0];
    float b = red[0][nf][l][1] + red[1][nf][l][1] + red[2][nf][l][1] + red[3][nf][l][1];
    int rep = blockIdx.x & (NREP - 1);
    atomicAdd(&stb[rep * ststride + 2 * t], (double)a);
    atomicAdd(&stb[rep * ststride + 2 * t + 1], (double)b);
  }
}

// ---------- i8 MFMA conv (row-linear K) + bf16 y-hat + fused stats ----------
template <int CI, int KK, int KROWP, int COB, int WPEU>
__global__ __launch_bounds__(256, WPEU) void cstat_kernel(
    const char* __restrict__ xin, const char* __restrict__ bp, int nft,
    double* __restrict__ stb, u16* __restrict__ yh) {
  constexpr int NCH = (KK == 1) ? CI / 64 : 3 * (KROWP / 64);
  constexpr int CPR = KROWP / 64;
  constexpr int NFW = COB / 16;
  constexpr int MF = 2;

  const int lane = threadIdx.x & 63;
  const int wave = threadIdx.x >> 6;
  const int mbase = blockIdx.x * 128 + wave * 32;

  uint abase[MF];
#pragma unroll
  for (int mf = 0; mf < MF; ++mf) {
    int p = mbase + mf * 16 + (lane & 15);
    if (KK == 1) {
      abase[mf] = (uint)p * CI;
    } else {
      int n = p >> 10, hw = p & 1023, h = hw >> 5, w = hw & 31;
      abase[mf] = (uint)((n * 34 + h) * 34 + w) * CI;
    }
  }
  const uint klane = (uint)(lane >> 4) * 16u;
  const uint blane = (uint)lane * 16u;

  i32x4 acc[MF][NFW];
#pragma unroll
  for (int i = 0; i < MF; ++i)
#pragma unroll
    for (int j = 0; j < NFW; ++j) acc[i][j] = {0, 0, 0, 0};

  auto chunk = [&](int c) {
    uint koff;
    if (KK == 1) {
      koff = (uint)c * 64u;
    } else {
      int r = c / CPR, o = (c - r * CPR) * 64;
      koff = (uint)(r * 34 * CI + o);
    }
    i32x4 af[MF];
#pragma unroll
    for (int mf = 0; mf < MF; ++mf)
      af[mf] = *(const i32x4*)(xin + (abase[mf] + koff + klane));
    i32x4 bfr[NFW];
#pragma unroll
    for (int nf = 0; nf < NFW; ++nf)
      bfr[nf] = *(const i32x4*)(bp + ((uint)((c * nft + nf) * 1024) + blane));
#pragma unroll
    for (int mf = 0; mf < MF; ++mf)
#pragma unroll
      for (int nf = 0; nf < NFW; ++nf)
        acc[mf][nf] = __builtin_amdgcn_mfma_i32_16x16x64_i8(af[mf], bfr[nf],
                                                            acc[mf][nf], 0, 0, 0);
  };

  if (KK == 1) {
#pragma unroll
    for (int c = 0; c < NCH; ++c) chunk(c);
  } else {
#pragma unroll 3
    for (int c = 0; c < NCH; ++c) chunk(c);
  }

  conv_epilogue<NFW, MF>(acc, lane, wave, mbase, yh, stb, 256);
}

// ---------- merged 1x1 conv: b1(64) + b2a(96) + b3a(16) = 176 ch, one xq pass ----------
__global__ __launch_bounds__(256, 3) void cstat3_kernel(
    const char* __restrict__ xin, const char* __restrict__ bp0,
    const char* __restrict__ bp1, const char* __restrict__ bp2,
    double* __restrict__ stM, u16* __restrict__ yh) {
  constexpr int NFW = 11;  // 4 (b1) + 6 (b2a) + 1 (b3a)
  constexpr int MF = 2;

  const int lane = threadIdx.x & 63;
  const int wave = threadIdx.x >> 6;
  const int mbase = blockIdx.x * 128 + wave * 32;

  uint abase[MF];
#pragma unroll
  for (int mf = 0; mf < MF; ++mf)
    abase[mf] = (uint)(mbase + mf * 16 + (lane & 15)) * 192u;
  const uint klane = (uint)(lane >> 4) * 16u;
  const uint blane = (uint)lane * 16u;

  i32x4 acc[MF][NFW];
#pragma unroll
  for (int i = 0; i < MF; ++i)
#pragma unroll
    for (int j = 0; j < NFW; ++j) acc[i][j] = {0, 0, 0, 0};

#pragma unroll
  for (int c = 0; c < 3; ++c) {
    i32x4 af[MF];
#pragma unroll
    for (int mf = 0; mf < MF; ++mf)
      af[mf] = *(const i32x4*)(xin + (abase[mf] + (uint)c * 64u + klane));
    i32x4 bfr[NFW];
#pragma unroll
    for (int nf = 0; nf < NFW; ++nf) {
      const char* src;
      if (nf < 4) src = bp0 + (c * 4 + nf) * 1024;
      else if (nf < 10) src = bp1 + (c * 6 + (nf - 4)) * 1024;
      else src = bp2 + c * 1024;
      bfr[nf] = *(const i32x4*)(src + blane);
    }
#pragma unroll
    for (int mf = 0; mf < MF; ++mf)
#pragma unroll
      for (int nf = 0; nf < NFW; ++nf)
        acc[mf][nf] = __builtin_amdgcn_mfma_i32_16x16x64_i8(af[mf], bfr[nf],
                                                            acc[mf][nf], 0, 0, 0);
  }

  conv_epilogue<NFW, MF>(acc, lane, wave, mbase, yh, stM, 384);
}

// ---------- BN+ReLU -> final f32 NCHW out; coefs inline from replicated stats ----------
__global__ __launch_bounds__(256) void bnout_kernel(const u16* __restrict__ yh,
                                                    const double* __restrict__ stb,
                                                    int ststride,
                                                    const float* __restrict__ g,
                                                    const float* __restrict__ be,
                                                    float* __restrict__ out, int cog) {
  int co = blockIdx.y, chunk = blockIdx.x, tid = threadIdx.x;
  double s1d = 0., s2d = 0.;
#pragma unroll
  for (int r = 0; r < NREP; ++r) {
    s1d += stb[r * ststride + 2 * co];
    s2d += stb[r * ststride + 2 * co + 1];
  }
  double m = s1d * (1.0 / PTOT);
  double v = s2d * (1.0 / PTOT) - m * m;
  double inv = 1.0 / sqrt(v + 1e-5);
  double c0d = (double)g[co] * inv;
  float c0 = (float)c0d;
  float c1 = (float)((double)be[co] - m * c0d);

  int p0 = chunk * 4096 + tid * 16;
  int n = p0 >> 10, hw = p0 & 1023;
  const u16* yp = yh + (size_t)co * PTOT + p0;
  float* op = out + (((size_t)(n * 256 + cog + co)) << 10) + hw;
#pragma unroll
  for (int half = 0; half < 2; ++half) {
    u16x8 r = *(const u16x8*)(yp + half * 8);
    f32x4 a, b;
#pragma unroll
    for (int e = 0; e < 4; ++e) {
      a[e] = fmaxf(fmaf(bf2f(r[e]), c0, c1), 0.f);
      b[e] = fmaxf(fmaf(bf2f(r[e + 4]), c0, c1), 0.f);
    }
    *(f32x4*)(op + half * 8) = a;
    *(f32x4*)(op + half * 8 + 4) = b;
  }
}

// ---------- BN+ReLU+quantize -> padded NHWC int8 ----------
template <int CO, int COP>
__global__ __launch_bounds__(256) void bnqpad_kernel(const u16* __restrict__ yh,
                                                     const double* __restrict__ stb,
                                                     int ststride,
                                                     const float* __restrict__ g,
                                                     const float* __restrict__ be,
                                                     char* __restrict__ q) {
  __shared__ float2 cfl[CO];
  __shared__ __align__(16) char tile[64][COP + 16];
  const int t = threadIdx.x;
  if (t < CO) {
    double s1d = 0., s2d = 0.;
#pragma unroll
    for (int r = 0; r < NREP; ++r) {
      s1d += stb[r * ststride + 2 * t];
      s2d += stb[r * ststride + 2 * t + 1];
    }
    double m = s1d * (1.0 / PTOT);
    double v = s2d * (1.0 / PTOT) - m * m;
    double inv = 1.0 / sqrt(v + 1e-5);
    double c0 = (double)g[t] * inv;
    cfl[t] = make_float2((float)c0, (float)((double)be[t] - m * c0));
  }
  __syncthreads();
  int p0 = blockIdx.x * 64;
  int lane = t & 63, sub = t >> 6;
#pragma unroll
  for (int i = 0; i < COP / 4; ++i) {
    int co = sub + i * 4;
    float2 cc = cfl[co];
    float z = fmaxf(fmaf(bf2f(yh[(size_t)co * PTOT + p0 + lane]), cc.x, cc.y), 0.f);
    tile[lane][co] = (char)min((int)rintf(z * 128.f), 127);  // z>=0 after relu
  }
  __syncthreads();
  for (int chunk = t; chunk < 64 * (COP / 16); chunk += 256) {
    int px = chunk / (COP / 16), c16 = chunk % (COP / 16);
    int p = p0 + px;
    int n = p >> 10, hw = p & 1023, h = hw >> 5, w = hw & 31;
    size_t dst = (((size_t)n * 34 + h + 1) * 34 + (w + 1)) * COP + c16 * 16;
    *(uint4*)&q[dst] = *(const uint4*)&tile[px][c16 * 16];
  }
}

extern "C" void kernel_launch(void* const* d_in, const int* in_sizes, int n_in,
                              void* d_out, int out_size, void* d_ws, size_t ws_size,
                              hipStream_t stream) {
  const float* x = (const float*)d_in[0];
  float* out = (float*)d_out;
  char* ws = (char*)d_ws;

  // ---- workspace layout (total 96,830,464 B) ----
  if (ws_size < 96830464ull) return;
  char* xq  = ws;                            // [PTOT][192] i8        = 25,165,824 B
  char* xpq = ws + 25165824ull;              // pooled [PTOT][192] i8 (dies after b4)
  char* q2a = xpq;                           // reuse: [128][34][34][96] +slack
  char* q3a = ws + 39371008ull;              // [128][34][34][16] +256
  char* q3b = ws + 41738752ull;              // [128][34][34][32] +256 (end 46,473,984)
  u16* yh   = (u16*)(ws + 50331648ull);      // [176][PTOT] bf16      = 46,137,344 B
  char* bpk = ws + 96468992ull;              // packed i8 weights        181,248 B
  double* stM = (double*)(ws + 96650240ull); // merged 176ch: NREP x 384 = 49,152 B
  double* st2 = (double*)(ws + 96699392ull); // b2b: NREP x 256 doubles = 32,768 B
  double* st4 = (double*)(ws + 96732160ull); // b4
  double* st3b = (double*)(ws + 96764928ull);// b3b
  double* st3c = (double*)(ws + 96797696ull);// b3c  (end 96,830,464)

  hipMemsetAsync(stM, 0, 180224, stream);  // all 5 stat regions

  WPtrs wp;
  const int widx[7] = {1, 5, 9, 13, 17, 21, 25};
  for (int i = 0; i < 7; ++i) wp.p[i] = (const float*)d_in[widx[i]];
  wpack_kernel<<<708, 256, 0, stream>>>(wp, bpk);

  quantx_kernel<<<dim3(16, 3, 128), 256, 0, stream>>>(x, xq);
  pool_kernel<<<6144, 256, 0, stream>>>(xq, xpq);

  dim3 grd(1024), blk(256);

  // ---- b4 (slot 6): pooled 1x1 192->32, out 224..255 (xpq dies after) ----
  cstat_kernel<192, 1, 192, 32, 4><<<grd, blk, 0, stream>>>(xpq, bpk + 175104, 2,
                                                            st4, yh);
  bnout_kernel<<<dim3(32, 32), 256, 0, stream>>>(yh, st4, 256, (const float*)d_in[27],
                                                 (const float*)d_in[28], out, 224);

  // zero borders of padded q buffers (q2a aliases dead xpq)
  border_kernel<<<dim3(128, 3), 256, 0, stream>>>(q2a, q3a, q3b);

  // ---- merged 1x1: b1 (ch 0..63) + b2a (64..159) + b3a (160..175), one xq pass ----
  cstat3_kernel<<<grd, blk, 0, stream>>>(xq, bpk + 0, bpk + 12288, bpk + 153600,
                                         stM, yh);
  bnout_kernel<<<dim3(32, 64), 256, 0, stream>>>(yh, stM, 384, (const float*)d_in[3],
                                                 (const float*)d_in[4], out, 0);
  bnqpad_kernel<96, 96><<<2048, 256, 0, stream>>>(yh + (size_t)64 * PTOT, stM + 128,
                                                  384, (const float*)d_in[7],
                                                  (const float*)d_in[8], q2a);
  bnqpad_kernel<16, 16><<<2048, 256, 0, stream>>>(yh + (size_t)160 * PTOT, stM + 320,
                                                  384, (const float*)d_in[15],
                                                  (const float*)d_in[16], q3a);

  // ---- b2b (slot 2): 3x3 96->128 row-linear K (KROWP=320), out 64..191 ----
  cstat_kernel<96, 9, 320, 128, 3><<<grd, blk, 0, stream>>>(q2a, bpk + 30720, 8,
                                                            st2, yh);
  bnout_kernel<<<dim3(32, 128), 256, 0, stream>>>(yh, st2, 256, (const float*)d_in[11],
                                                  (const float*)d_in[12], out, 64);

  // ---- b3b (slot 4): 3x3 16->32 row-linear K (KROWP=64) -> q3b ----
  cstat_kernel<16, 9, 64, 32, 4><<<grd, blk, 0, stream>>>(q3a, bpk + 156672, 2,
                                                          st3b, yh);
  bnqpad_kernel<32, 32><<<2048, 256, 0, stream>>>(yh, st3b, 256, (const float*)d_in[19],
                                                  (const float*)d_in[20], q3b);

  // ---- b3c (slot 5): 3x3 32->32 row-linear K (KROWP=128), out 192..223 ----
  cstat_kernel<32, 9, 128, 32, 4><<<grd, blk, 0, stream>>>(q3b, bpk + 162816, 2,
                                                           st3c, yh);
  bnout_kernel<<<dim3(32, 32), 256, 0, stream>>>(yh, st3c, 256, (const float*)d_in[23],
                                                 (const float*)d_in[24], out, 192);
}

// Round 12
// 242.838 us; speedup vs baseline: 1.0277x; 1.0277x over previous
//
#include <hip/hip_runtime.h>

typedef unsigned short u16;
typedef unsigned int u32;
typedef __attribute__((ext_vector_type(4))) int i32x4;
typedef __attribute__((ext_vector_type(4))) float f32x4;
typedef __attribute__((ext_vector_type(4))) u16 u16x4;
typedef __attribute__((ext_vector_type(8))) u16 u16x8;

#define PTOT 131072   // 128 images * 32*32 pixels
#define NREP 16       // stat accumulator replicas (atomic de-contention)

// ---------- helpers ----------
static __device__ __forceinline__ int qi8(float v) {  // round-half-even, clip +-127
  int q = (int)rintf(v * 128.f);
  return max(-127, min(127, q));
}
static __device__ __forceinline__ u16 bf_rne(float v) { // round-nearest-even bf16
  u32 u = __float_as_uint(v);
  u += 0x7fffu + ((u >> 16) & 1u);
  return (u16)(u >> 16);
}
static __device__ __forceinline__ float bf2f(u16 v) {
  return __uint_as_float((u32)v << 16);
}

// ---------- weight quantize + i8 MFMA fragment packing (row-linear K) ----------
// packed: [NCH][NF][64 lanes][16 B]; co = nf*16+(lane&15),
// k = c*64 + (lane>>4)*16 + j over row-linear K: r = k/KROWP, kk = k%KROWP;
// kk < 3*CIr -> (kh=r, kw=kk/CIr, ci=kk%CIr); else zero (row tail pad).
struct WPtrs { const float* p[7]; };

__global__ void wpack_kernel(WPtrs wp, char* __restrict__ o) {
  // {byte_off, CIr, KROWP, KH, Co}   (len = NCH*NF*1024)
  static const int S[7][5] = {
      {0,      192, 192, 1, 64},   // b1   NCH=3 NF=4  12288
      {12288,  192, 192, 1, 96},   // b2a  NCH=3 NF=6  18432
      {30720,  96,  320, 3, 128},  // b2b  NCH=15 NF=8 122880
      {153600, 192, 192, 1, 16},   // b3a  NCH=3 NF=1  3072
      {156672, 16,  64,  3, 32},   // b3b  NCH=3 NF=2  6144
      {162816, 32,  128, 3, 32},   // b3c  NCH=6 NF=2  12288
      {175104, 192, 192, 1, 32},   // b4   NCH=3 NF=2  6144
  };
  int idx = blockIdx.x * 256 + threadIdx.x;
  if (idx >= 181248) return;
  int s = 0;
#pragma unroll
  for (int i = 1; i < 7; ++i)
    if (idx >= S[i][0]) s = i;
  int local = idx - S[s][0];
  int CIr = S[s][1], KROWP = S[s][2], KH = S[s][3], Co = S[s][4];
  int j = local & 15, lane = (local >> 4) & 63, f = local >> 10;
  int NF = Co >> 4;
  int c = f / NF, nf = f - c * NF;
  int co = nf * 16 + (lane & 15);
  int k = c * 64 + ((lane >> 4) << 4) + j;
  int r = k / KROWP, kk = k - r * KROWP;
  char val = 0;
  if (kk < 3 * CIr || KH == 1) {
    int kw = (KH == 1) ? 0 : (kk / CIr);
    int ci = (KH == 1) ? kk : (kk - kw * CIr);
    val = (char)qi8(wp.p[s][(((size_t)co * CIr + ci) * KH + r) * KH + kw]);
  }
  o[idx] = val;
}

// ---------- quantize x: NCHW f32 -> NHWC int8 ----------
__global__ __launch_bounds__(256) void quantx_kernel(const float* __restrict__ x,
                                                     char* __restrict__ xq) {
  __shared__ __align__(16) char tile[64][80];
  int n = blockIdx.z, hwb = blockIdx.x * 64, cb = blockIdx.y * 64;
  int lane = threadIdx.x & 63, sub = threadIdx.x >> 6;
#pragma unroll
  for (int i = 0; i < 16; ++i) {
    int c = sub + i * 4;
    float v = x[(((size_t)n * 192 + cb + c) << 10) + hwb + lane];
    tile[lane][c] = (char)qi8(v);
  }
  __syncthreads();
  int t = threadIdx.x, px = t >> 2, c16 = t & 3;
  uint4 v = *(const uint4*)&tile[px][c16 * 16];
  *(uint4*)&xq[(((size_t)n << 10) + hwb + px) * 192 + cb + c16 * 16] = v;
}

// ---------- maxpool 3x3 s1 p1 on int8 NHWC ----------
__global__ __launch_bounds__(256) void pool_kernel(const char* __restrict__ xq,
                                                   char* __restrict__ xpq) {
  int idx = blockIdx.x * 256 + threadIdx.x;
  int c16 = idx % 12;
  int p = idx / 12;
  int n = p >> 10, hw = p & 1023, h = hw >> 5, w = hw & 31;
  int m[16];
#pragma unroll
  for (int j = 0; j < 16; ++j) m[j] = -127;
  for (int dh = -1; dh <= 1; ++dh) {
    int hh = h + dh; if (hh < 0 || hh > 31) continue;
    for (int dw = -1; dw <= 1; ++dw) {
      int ww = w + dw; if (ww < 0 || ww > 31) continue;
      uint4 v = *(const uint4*)&xq[((((size_t)n << 5) + hh) * 32 + ww) * 192 + c16 * 16];
      const char* bb = reinterpret_cast<const char*>(&v);
#pragma unroll
      for (int t = 0; t < 16; ++t) {
        int b = (int)bb[t];
        m[t] = b > m[t] ? b : m[t];
      }
    }
  }
  uint4 o;
  char* ob = reinterpret_cast<char*>(&o);
#pragma unroll
  for (int t = 0; t < 16; ++t) ob[t] = (char)m[t];
  *(uint4*)&xpq[(size_t)p * 192 + c16 * 16] = o;
}

// ---------- zero the 1-px borders of padded q buffers ----------
__global__ __launch_bounds__(256) void border_kernel(char* __restrict__ q2a,
                                                     char* __restrict__ q3a,
                                                     char* __restrict__ q3b) {
  int img = blockIdx.x, buf = blockIdx.y;
  char* base; int C;
  if (buf == 0) { base = q2a; C = 96; }
  else if (buf == 1) { base = q3a; C = 16; }
  else { base = q3b; C = 32; }
  char* ib = base + (size_t)img * 34 * 34 * C;
  int nch = C >> 4;
  uint4 z = {0, 0, 0, 0};
  for (int idx = threadIdx.x; idx < 132 * nch; idx += 256) {
    int b = idx / nch, cc = idx - b * nch;
    int h, w;
    if (b < 34) { h = 0; w = b; }
    else if (b < 68) { h = 33; w = b - 34; }
    else { int s = b - 68; h = 1 + (s >> 1); w = (s & 1) ? 33 : 0; }
    *(uint4*)(ib + ((h * 34 + w) * C + cc * 16)) = z;
  }
}

// ---------- shared conv epilogue: yh write + stats reduce + atomics ----------
template <int NFW, int MF>
static __device__ __forceinline__ void conv_epilogue(
    i32x4 (&acc)[MF][NFW], int lane, int wave, int mbase,
    u16* __restrict__ yh, double* __restrict__ stb, int ststride) {
  constexpr int COB = NFW * 16;
  float yv[MF][NFW][4];
#pragma unroll
  for (int mf = 0; mf < MF; ++mf)
#pragma unroll
    for (int nf = 0; nf < NFW; ++nf) {
      int col = nf * 16 + (lane & 15);
      int pix = mbase + mf * 16 + ((lane >> 4) << 2);
      u16x4 o;
#pragma unroll
      for (int r = 0; r < 4; ++r) {
        float v = (float)acc[mf][nf][r] * 6.103515625e-05f;  // 2^-14 (exact)
        yv[mf][nf][r] = v;
        o[r] = bf_rne(v);
      }
      *(u16x4*)&yh[(size_t)col * PTOT + pix] = o;
    }

  float s1[NFW], s2[NFW];
#pragma unroll
  for (int nf = 0; nf < NFW; ++nf) { s1[nf] = 0.f; s2[nf] = 0.f; }
#pragma unroll
  for (int mf = 0; mf < MF; ++mf)
#pragma unroll
    for (int nf = 0; nf < NFW; ++nf)
#pragma unroll
      for (int r = 0; r < 4; ++r) {
        float v = yv[mf][nf][r];
        s1[nf] += v;
        s2[nf] += v * v;
      }
#pragma unroll
  for (int m = 16; m <= 32; m <<= 1)
#pragma unroll
    for (int nf = 0; nf < NFW; ++nf) {
      s1[nf] += __shfl_xor(s1[nf], m);
      s2[nf] += __shfl_xor(s2[nf], m);
    }
  __shared__ float red[4][NFW][16][2];
  if (lane < 16)
#pragma unroll
    for (int nf = 0; nf < NFW; ++nf) {
      red[wave][nf][lane][0] = s1[nf];
      red[wave][nf][lane][1] = s2[nf];
    }
  __syncthreads();
  const int t = threadIdx.x;
  if (t < COB) {
    int nf = t >> 4, l = t & 15;
    float a = red[0][nf][l][0] + red[1][nf][l][0] + red[2][nf][l][0] + red[3][nf][l][0];
    float b = red[0][nf][l][1] + red[1][nf][l][1] + red[2][nf][l][1] + red[3][nf][l][1];
    int rep = blockIdx.x & (NREP - 1);
    atomicAdd(&stb[rep * ststride + 2 * t], (double)a);
    atomicAdd(&stb[rep * ststride + 2 * t + 1], (double)b);
  }
}

// ---------- 1x1 i8 MFMA conv + bf16 y-hat + fused stats ----------
template <int CI, int COB, int WPEU>
__global__ __launch_bounds__(256, WPEU) void cstat_kernel(
    const char* __restrict__ xin, const char* __restrict__ bp, int nft,
    double* __restrict__ stb, u16* __restrict__ yh) {
  constexpr int NCH = CI / 64;
  constexpr int NFW = COB / 16;
  constexpr int MF = 2;

  const int lane = threadIdx.x & 63;
  const int wave = threadIdx.x >> 6;
  const int mbase = blockIdx.x * 128 + wave * 32;

  uint abase[MF];
#pragma unroll
  for (int mf = 0; mf < MF; ++mf)
    abase[mf] = (uint)(mbase + mf * 16 + (lane & 15)) * CI;
  const uint klane = (uint)(lane >> 4) * 16u;
  const uint blane = (uint)lane * 16u;

  i32x4 acc[MF][NFW];
#pragma unroll
  for (int i = 0; i < MF; ++i)
#pragma unroll
    for (int j = 0; j < NFW; ++j) acc[i][j] = {0, 0, 0, 0};

#pragma unroll
  for (int c = 0; c < NCH; ++c) {
    i32x4 af[MF];
#pragma unroll
    for (int mf = 0; mf < MF; ++mf)
      af[mf] = *(const i32x4*)(xin + (abase[mf] + (uint)c * 64u + klane));
    i32x4 bfr[NFW];
#pragma unroll
    for (int nf = 0; nf < NFW; ++nf)
      bfr[nf] = *(const i32x4*)(bp + ((uint)((c * nft + nf) * 1024) + blane));
#pragma unroll
    for (int mf = 0; mf < MF; ++mf)
#pragma unroll
      for (int nf = 0; nf < NFW; ++nf)
        acc[mf][nf] = __builtin_amdgcn_mfma_i32_16x16x64_i8(af[mf], bfr[nf],
                                                            acc[mf][nf], 0, 0, 0);
  }

  conv_epilogue<NFW, MF>(acc, lane, wave, mbase, yh, stb, 256);
}

// ---------- 3x3 i8 MFMA conv, LDS-staged A tile (row-linear K) ----------
// Block = 128 px = 4 consecutive rows of one image. A-footprint = padded rows
// h0..h0+5, full width: ONE contiguous range of 6*34*CI bytes -> linear staged
// into LDS (single barrier, read-only after). +64 B slack absorbs the row-tail
// window overrun (those bytes hit zero weights -> contribute exactly 0).
template <int CI, int KROWP, int COB, int WPEU>
__global__ __launch_bounds__(256, WPEU) void cstat9_kernel(
    const char* __restrict__ xin, const char* __restrict__ bp, int nft,
    double* __restrict__ stb, u16* __restrict__ yh) {
  constexpr int CPR = KROWP / 64;
  constexpr int NCH = 3 * CPR;
  constexpr int NFW = COB / 16;
  constexpr int MF = 2;
  constexpr int TILE = 6 * 34 * CI;
  constexpr int TV = TILE / 16;

  __shared__ __align__(16) char atile[TILE + 64];

  const int lane = threadIdx.x & 63;
  const int wave = threadIdx.x >> 6;
  const int mbase = blockIdx.x * 128 + wave * 32;

  {
    int p0 = blockIdx.x * 128;
    int n = p0 >> 10, h0 = (p0 & 1023) >> 5;
    const char* src = xin + (size_t)((n * 34 + h0) * 34) * CI;
    for (int s = threadIdx.x; s < TV; s += 256)
      *(uint4*)&atile[s * 16] = *(const uint4*)(src + (size_t)s * 16);
  }
  __syncthreads();

  uint albase[MF];
#pragma unroll
  for (int mf = 0; mf < MF; ++mf) {
    int lp = wave * 32 + mf * 16 + (lane & 15);  // local pixel in [0,128)
    albase[mf] = (uint)(((lp >> 5) * 34 + (lp & 31)) * CI);
  }
  const uint klane = (uint)(lane >> 4) * 16u;
  const uint blane = (uint)lane * 16u;

  i32x4 acc[MF][NFW];
#pragma unroll
  for (int i = 0; i < MF; ++i)
#pragma unroll
    for (int j = 0; j < NFW; ++j) acc[i][j] = {0, 0, 0, 0};

#pragma unroll 2
  for (int c = 0; c < NCH; ++c) {
    int rr = c / CPR, o = (c - rr * CPR) * 64;
    uint koff = (uint)(rr * 34 * CI + o);
    i32x4 af[MF];
#pragma unroll
    for (int mf = 0; mf < MF; ++mf)
      af[mf] = *(const i32x4*)&atile[albase[mf] + koff + klane];
    i32x4 bfr[NFW];
#pragma unroll
    for (int nf = 0; nf < NFW; ++nf)
      bfr[nf] = *(const i32x4*)(bp + ((uint)((c * nft + nf) * 1024) + blane));
#pragma unroll
    for (int mf = 0; mf < MF; ++mf)
#pragma unroll
      for (int nf = 0; nf < NFW; ++nf)
        acc[mf][nf] = __builtin_amdgcn_mfma_i32_16x16x64_i8(af[mf], bfr[nf],
                                                            acc[mf][nf], 0, 0, 0);
  }

  conv_epilogue<NFW, MF>(acc, lane, wave, mbase, yh, stb, 256);
}

// ---------- BN+ReLU -> final f32 NCHW out; coefs inline from replicated stats ----------
__global__ __launch_bounds__(256) void bnout_kernel(const u16* __restrict__ yh,
                                                    const double* __restrict__ stb,
                                                    int ststride,
                                                    const float* __restrict__ g,
                                                    const float* __restrict__ be,
                                                    float* __restrict__ out, int cog) {
  int co = blockIdx.y, chunk = blockIdx.x, tid = threadIdx.x;
  double s1d = 0., s2d = 0.;
#pragma unroll
  for (int r = 0; r < NREP; ++r) {
    s1d += stb[r * ststride + 2 * co];
    s2d += stb[r * ststride + 2 * co + 1];
  }
  double m = s1d * (1.0 / PTOT);
  double v = s2d * (1.0 / PTOT) - m * m;
  double inv = 1.0 / sqrt(v + 1e-5);
  double c0d = (double)g[co] * inv;
  float c0 = (float)c0d;
  float c1 = (float)((double)be[co] - m * c0d);

  int p0 = chunk * 4096 + tid * 16;
  int n = p0 >> 10, hw = p0 & 1023;
  const u16* yp = yh + (size_t)co * PTOT + p0;
  float* op = out + (((size_t)(n * 256 + cog + co)) << 10) + hw;
#pragma unroll
  for (int half = 0; half < 2; ++half) {
    u16x8 r = *(const u16x8*)(yp + half * 8);
    f32x4 a, b;
#pragma unroll
    for (int e = 0; e < 4; ++e) {
      a[e] = fmaxf(fmaf(bf2f(r[e]), c0, c1), 0.f);
      b[e] = fmaxf(fmaf(bf2f(r[e + 4]), c0, c1), 0.f);
    }
    *(f32x4*)(op + half * 8) = a;
    *(f32x4*)(op + half * 8 + 4) = b;
  }
}

// ---------- BN+ReLU+quantize -> padded NHWC int8 ----------
template <int CO, int COP>
__global__ __launch_bounds__(256) void bnqpad_kernel(const u16* __restrict__ yh,
                                                     const double* __restrict__ stb,
                                                     int ststride,
                                                     const float* __restrict__ g,
                                                     const float* __restrict__ be,
                                                     char* __restrict__ q) {
  __shared__ float2 cfl[CO];
  __shared__ __align__(16) char tile[64][COP + 16];
  const int t = threadIdx.x;
  if (t < CO) {
    double s1d = 0., s2d = 0.;
#pragma unroll
    for (int r = 0; r < NREP; ++r) {
      s1d += stb[r * ststride + 2 * t];
      s2d += stb[r * ststride + 2 * t + 1];
    }
    double m = s1d * (1.0 / PTOT);
    double v = s2d * (1.0 / PTOT) - m * m;
    double inv = 1.0 / sqrt(v + 1e-5);
    double c0 = (double)g[t] * inv;
    cfl[t] = make_float2((float)c0, (float)((double)be[t] - m * c0));
  }
  __syncthreads();
  int p0 = blockIdx.x * 64;
  int lane = t & 63, sub = t >> 6;
#pragma unroll
  for (int i = 0; i < COP / 4; ++i) {
    int co = sub + i * 4;
    float2 cc = cfl[co];
    float z = fmaxf(fmaf(bf2f(yh[(size_t)co * PTOT + p0 + lane]), cc.x, cc.y), 0.f);
    tile[lane][co] = (char)min((int)rintf(z * 128.f), 127);  // z>=0 after relu
  }
  __syncthreads();
  for (int chunk = t; chunk < 64 * (COP / 16); chunk += 256) {
    int px = chunk / (COP / 16), c16 = chunk % (COP / 16);
    int p = p0 + px;
    int n = p >> 10, hw = p & 1023, h = hw >> 5, w = hw & 31;
    size_t dst = (((size_t)n * 34 + h + 1) * 34 + (w + 1)) * COP + c16 * 16;
    *(uint4*)&q[dst] = *(const uint4*)&tile[px][c16 * 16];
  }
}

extern "C" void kernel_launch(void* const* d_in, const int* in_sizes, int n_in,
                              void* d_out, int out_size, void* d_ws, size_t ws_size,
                              hipStream_t stream) {
  const float* x = (const float*)d_in[0];
  float* out = (float*)d_out;
  char* ws = (char*)d_ws;

  // ---- workspace layout (total 84,296,704 B) ----
  if (ws_size < 84296704ull) return;
  char* xq  = ws;                            // [PTOT][192] i8        = 25,165,824 B
  char* xpq = ws + 25165824ull;              // pooled [PTOT][192] i8 (dies after b4)
  char* q2a = xpq;                           // reuse: [128][34][34][96] +slack
  char* q3a = ws + 39371008ull;              // [128][34][34][16] +256
  char* q3b = ws + 41738752ull;              // [128][34][34][32] +256
  u16* yh   = (u16*)(ws + 50331648ull);      // [<=128][PTOT] bf16    = 33,554,432 B
  char* bpk = ws + 83886080ull;              // packed i8 weights        181,248 B
  double* st = (double*)(ws + 84067328ull);  // 7 x NREP x 256 doubles   229,376 B

  hipMemsetAsync(st, 0, 7 * NREP * 256 * 8, stream);

  WPtrs wp;
  const int widx[7] = {1, 5, 9, 13, 17, 21, 25};
  for (int i = 0; i < 7; ++i) wp.p[i] = (const float*)d_in[widx[i]];
  wpack_kernel<<<708, 256, 0, stream>>>(wp, bpk);

  quantx_kernel<<<dim3(16, 3, 128), 256, 0, stream>>>(x, xq);
  pool_kernel<<<6144, 256, 0, stream>>>(xq, xpq);

  dim3 grd(1024), blk(256);
  double* stB[7];
  for (int b = 0; b < 7; ++b) stB[b] = st + (size_t)b * NREP * 256;

  // ---- b4 (slot 6): pooled 1x1 192->32, out 224..255 (xpq dies after) ----
  cstat_kernel<192, 32, 4><<<grd, blk, 0, stream>>>(xpq, bpk + 175104, 2, stB[6], yh);
  bnout_kernel<<<dim3(32, 32), 256, 0, stream>>>(yh, stB[6], 256, (const float*)d_in[27],
                                                 (const float*)d_in[28], out, 224);

  // zero borders of padded q buffers (q2a aliases dead xpq)
  border_kernel<<<dim3(128, 3), 256, 0, stream>>>(q2a, q3a, q3b);

  // ---- b1 (slot 0): 1x1 192->64, out 0..63 ----
  cstat_kernel<192, 64, 4><<<grd, blk, 0, stream>>>(xq, bpk + 0, 4, stB[0], yh);
  bnout_kernel<<<dim3(32, 64), 256, 0, stream>>>(yh, stB[0], 256, (const float*)d_in[3],
                                                 (const float*)d_in[4], out, 0);

  // ---- b2a (slot 1): 1x1 192->96 -> q2a ----
  cstat_kernel<192, 96, 4><<<grd, blk, 0, stream>>>(xq, bpk + 12288, 6, stB[1], yh);
  bnqpad_kernel<96, 96><<<2048, 256, 0, stream>>>(yh, stB[1], 256, (const float*)d_in[7],
                                                  (const float*)d_in[8], q2a);

  // ---- b2b (slot 2): 3x3 96->128, LDS-A, row-linear K (KROWP=320), out 64..191 ----
  cstat9_kernel<96, 320, 128, 3><<<grd, blk, 0, stream>>>(q2a, bpk + 30720, 8,
                                                          stB[2], yh);
  bnout_kernel<<<dim3(32, 128), 256, 0, stream>>>(yh, stB[2], 256, (const float*)d_in[11],
                                                  (const float*)d_in[12], out, 64);

  // ---- b3a (slot 3): 1x1 192->16 -> q3a ----
  cstat_kernel<192, 16, 4><<<grd, blk, 0, stream>>>(xq, bpk + 153600, 1, stB[3], yh);
  bnqpad_kernel<16, 16><<<2048, 256, 0, stream>>>(yh, stB[3], 256, (const float*)d_in[15],
                                                  (const float*)d_in[16], q3a);

  // ---- b3b (slot 4): 3x3 16->32, LDS-A (KROWP=64) -> q3b ----
  cstat9_kernel<16, 64, 32, 4><<<grd, blk, 0, stream>>>(q3a, bpk + 156672, 2,
                                                        stB[4], yh);
  bnqpad_kernel<32, 32><<<2048, 256, 0, stream>>>(yh, stB[4], 256, (const float*)d_in[19],
                                                  (const float*)d_in[20], q3b);

  // ---- b3c (slot 5): 3x3 32->32, LDS-A (KROWP=128), out 192..223 ----
  cstat9_kernel<32, 128, 32, 4><<<grd, blk, 0, stream>>>(q3b, bpk + 162816, 2,
                                                         stB[5], yh);
  bnout_kernel<<<dim3(32, 32), 256, 0, stream>>>(yh, stB[5], 256, (const float*)d_in[23],
                                                 (const float*)d_in[24], out, 192);
}

// Round 13
// 215.589 us; speedup vs baseline: 1.1576x; 1.1264x over previous
//
#include <hip/hip_runtime.h>

typedef unsigned short u16;
typedef unsigned int u32;
typedef __attribute__((ext_vector_type(4))) int i32x4;
typedef __attribute__((ext_vector_type(4))) float f32x4;
typedef __attribute__((ext_vector_type(4))) u16 u16x4;
typedef __attribute__((ext_vector_type(8))) u16 u16x8;

#define PTOT 131072   // 128 images * 32*32 pixels
#define NREP 16       // stat accumulator replicas (atomic de-contention)

// ---------- helpers ----------
static __device__ __forceinline__ int qi8(float v) {  // round-half-even, clip +-127
  int q = (int)rintf(v * 128.f);
  return max(-127, min(127, q));
}
static __device__ __forceinline__ u16 bf_rne(float v) { // round-nearest-even bf16
  u32 u = __float_as_uint(v);
  u += 0x7fffu + ((u >> 16) & 1u);
  return (u16)(u >> 16);
}
static __device__ __forceinline__ float bf2f(u16 v) {
  return __uint_as_float((u32)v << 16);
}

// ---------- weight quantize + i8 MFMA fragment packing (row-linear K) ----------
struct WPtrs { const float* p[7]; };

__global__ void wpack_kernel(WPtrs wp, char* __restrict__ o) {
  // {byte_off, CIr, KROWP, KH, Co}   (len = NCH*NF*1024)
  static const int S[7][5] = {
      {0,      192, 192, 1, 64},   // b1   NCH=3 NF=4  12288
      {12288,  192, 192, 1, 96},   // b2a  NCH=3 NF=6  18432
      {30720,  96,  320, 3, 128},  // b2b  NCH=15 NF=8 122880
      {153600, 192, 192, 1, 16},   // b3a  NCH=3 NF=1  3072
      {156672, 16,  64,  3, 32},   // b3b  NCH=3 NF=2  6144
      {162816, 32,  128, 3, 32},   // b3c  NCH=6 NF=2  12288
      {175104, 192, 192, 1, 32},   // b4   NCH=3 NF=2  6144
  };
  int idx = blockIdx.x * 256 + threadIdx.x;
  if (idx >= 181248) return;
  int s = 0;
#pragma unroll
  for (int i = 1; i < 7; ++i)
    if (idx >= S[i][0]) s = i;
  int local = idx - S[s][0];
  int CIr = S[s][1], KROWP = S[s][2], KH = S[s][3], Co = S[s][4];
  int j = local & 15, lane = (local >> 4) & 63, f = local >> 10;
  int NF = Co >> 4;
  int c = f / NF, nf = f - c * NF;
  int co = nf * 16 + (lane & 15);
  int k = c * 64 + ((lane >> 4) << 4) + j;
  int r = k / KROWP, kk = k - r * KROWP;
  char val = 0;
  if (kk < 3 * CIr || KH == 1) {
    int kw = (KH == 1) ? 0 : (kk / CIr);
    int ci = (KH == 1) ? kk : (kk - kw * CIr);
    val = (char)qi8(wp.p[s][(((size_t)co * CIr + ci) * KH + r) * KH + kw]);
  }
  o[idx] = val;
}

// ---------- quantize x: NCHW f32 -> NHWC int8 ----------
__global__ __launch_bounds__(256) void quantx_kernel(const float* __restrict__ x,
                                                     char* __restrict__ xq) {
  __shared__ __align__(16) char tile[64][80];
  int n = blockIdx.z, hwb = blockIdx.x * 64, cb = blockIdx.y * 64;
  int lane = threadIdx.x & 63, sub = threadIdx.x >> 6;
#pragma unroll
  for (int i = 0; i < 16; ++i) {
    int c = sub + i * 4;
    float v = x[(((size_t)n * 192 + cb + c) << 10) + hwb + lane];
    tile[lane][c] = (char)qi8(v);
  }
  __syncthreads();
  int t = threadIdx.x, px = t >> 2, c16 = t & 3;
  uint4 v = *(const uint4*)&tile[px][c16 * 16];
  *(uint4*)&xq[(((size_t)n << 10) + hwb + px) * 192 + cb + c16 * 16] = v;
}

// ---------- maxpool 3x3 s1 p1 on int8 NHWC ----------
__global__ __launch_bounds__(256) void pool_kernel(const char* __restrict__ xq,
                                                   char* __restrict__ xpq) {
  int idx = blockIdx.x * 256 + threadIdx.x;
  int c16 = idx % 12;
  int p = idx / 12;
  int n = p >> 10, hw = p & 1023, h = hw >> 5, w = hw & 31;
  int m[16];
#pragma unroll
  for (int j = 0; j < 16; ++j) m[j] = -127;
  for (int dh = -1; dh <= 1; ++dh) {
    int hh = h + dh; if (hh < 0 || hh > 31) continue;
    for (int dw = -1; dw <= 1; ++dw) {
      int ww = w + dw; if (ww < 0 || ww > 31) continue;
      uint4 v = *(const uint4*)&xq[((((size_t)n << 5) + hh) * 32 + ww) * 192 + c16 * 16];
      const char* bb = reinterpret_cast<const char*>(&v);
#pragma unroll
      for (int t = 0; t < 16; ++t) {
        int b = (int)bb[t];
        m[t] = b > m[t] ? b : m[t];
      }
    }
  }
  uint4 o;
  char* ob = reinterpret_cast<char*>(&o);
#pragma unroll
  for (int t = 0; t < 16; ++t) ob[t] = (char)m[t];
  *(uint4*)&xpq[(size_t)p * 192 + c16 * 16] = o;
}

// ---------- zero the 1-px borders of padded q buffers ----------
__global__ __launch_bounds__(256) void border_kernel(char* __restrict__ q2a,
                                                     char* __restrict__ q3a,
                                                     char* __restrict__ q3b) {
  int img = blockIdx.x, buf = blockIdx.y;
  char* base; int C;
  if (buf == 0) { base = q2a; C = 96; }
  else if (buf == 1) { base = q3a; C = 16; }
  else { base = q3b; C = 32; }
  char* ib = base + (size_t)img * 34 * 34 * C;
  int nch = C >> 4;
  uint4 z = {0, 0, 0, 0};
  for (int idx = threadIdx.x; idx < 132 * nch; idx += 256) {
    int b = idx / nch, cc = idx - b * nch;
    int h, w;
    if (b < 34) { h = 0; w = b; }
    else if (b < 68) { h = 33; w = b - 34; }
    else { int s = b - 68; h = 1 + (s >> 1); w = (s & 1) ? 33 : 0; }
    *(uint4*)(ib + ((h * 34 + w) * C + cc * 16)) = z;
  }
}

// ---------- shared conv epilogue (runtime nfw guard) ----------
template <int NFW, int MF>
static __device__ __forceinline__ void conv_epilogue(
    i32x4 (&acc)[MF][NFW], int nfw, int lane, int wave, int mbase,
    u16* __restrict__ yh, double* __restrict__ stb, int ststride) {
  float yv[MF][NFW][4];
#pragma unroll
  for (int mf = 0; mf < MF; ++mf)
#pragma unroll
    for (int nf = 0; nf < NFW; ++nf)
      if (nf < nfw) {
        int col = nf * 16 + (lane & 15);
        int pix = mbase + mf * 16 + ((lane >> 4) << 2);
        u16x4 o;
#pragma unroll
        for (int r = 0; r < 4; ++r) {
          float v = (float)acc[mf][nf][r] * 6.103515625e-05f;  // 2^-14 (exact)
          yv[mf][nf][r] = v;
          o[r] = bf_rne(v);
        }
        *(u16x4*)&yh[(size_t)col * PTOT + pix] = o;
      }

  float s1[NFW], s2[NFW];
#pragma unroll
  for (int nf = 0; nf < NFW; ++nf) { s1[nf] = 0.f; s2[nf] = 0.f; }
#pragma unroll
  for (int mf = 0; mf < MF; ++mf)
#pragma unroll
    for (int nf = 0; nf < NFW; ++nf)
      if (nf < nfw)
#pragma unroll
        for (int r = 0; r < 4; ++r) {
          float v = yv[mf][nf][r];
          s1[nf] += v;
          s2[nf] += v * v;
        }
#pragma unroll
  for (int m = 16; m <= 32; m <<= 1)
#pragma unroll
    for (int nf = 0; nf < NFW; ++nf) {
      s1[nf] += __shfl_xor(s1[nf], m);
      s2[nf] += __shfl_xor(s2[nf], m);
    }
  __shared__ float red[4][NFW][16][2];
  if (lane < 16)
#pragma unroll
    for (int nf = 0; nf < NFW; ++nf) {
      red[wave][nf][lane][0] = s1[nf];
      red[wave][nf][lane][1] = s2[nf];
    }
  __syncthreads();
  const int t = threadIdx.x;
  if (t < 16 * nfw) {
    int nf = t >> 4, l = t & 15;
    float a = red[0][nf][l][0] + red[1][nf][l][0] + red[2][nf][l][0] + red[3][nf][l][0];
    float b = red[0][nf][l][1] + red[1][nf][l][1] + red[2][nf][l][1] + red[3][nf][l][1];
    int rep = blockIdx.x & (NREP - 1);
    atomicAdd(&stb[rep * ststride + 2 * t], (double)a);
    atomicAdd(&stb[rep * ststride + 2 * t + 1], (double)b);
  }
}

// ---------- merged 1x1 convs: blockIdx.y selects branch {b1,b2a,b3a,b4} ----------
// Each block runs ONE branch's loop (nfw<=6 guarded); register footprint =
// NFW=6 path (= b2a, proven at WPEU=4). 4 launches -> 1.
__global__ __launch_bounds__(256, 4) void cstat1x1_kernel(
    const char* __restrict__ xq, const char* __restrict__ xpq,
    const char* __restrict__ bpk, double* __restrict__ st, u16* __restrict__ yh) {
  constexpr int NFW = 6;
  constexpr int MF = 2;
  const int b = blockIdx.y;  // uniform
  const int nfw = (b == 0) ? 4 : (b == 1) ? 6 : (b == 2) ? 1 : 2;
  const int bpo = (b == 0) ? 0 : (b == 1) ? 12288 : (b == 2) ? 153600 : 175104;
  const int sto = (b == 0) ? 0 : (b == 1) ? 256 * NREP
                           : (b == 2) ? 3 * 256 * NREP : 6 * 256 * NREP;
  const int yho = (b == 0) ? 0 : (b == 1) ? 64 : (b == 2) ? 160 : 176;
  const char* xin = (b == 3) ? xpq : xq;
  const char* bp = bpk + bpo;
  double* stb = st + sto;
  u16* yhb = yh + (size_t)yho * PTOT;

  const int lane = threadIdx.x & 63;
  const int wave = threadIdx.x >> 6;
  const int mbase = blockIdx.x * 128 + wave * 32;

  uint abase[MF];
#pragma unroll
  for (int mf = 0; mf < MF; ++mf)
    abase[mf] = (uint)(mbase + mf * 16 + (lane & 15)) * 192u;
  const uint klane = (uint)(lane >> 4) * 16u;
  const uint blane = (uint)lane * 16u;

  i32x4 acc[MF][NFW];
#pragma unroll
  for (int i = 0; i < MF; ++i)
#pragma unroll
    for (int j = 0; j < NFW; ++j) acc[i][j] = {0, 0, 0, 0};

#pragma unroll
  for (int c = 0; c < 3; ++c) {
    i32x4 af[MF];
#pragma unroll
    for (int mf = 0; mf < MF; ++mf)
      af[mf] = *(const i32x4*)(xin + (abase[mf] + (uint)c * 64u + klane));
    i32x4 bfr[NFW];
#pragma unroll
    for (int nf = 0; nf < NFW; ++nf)
      if (nf < nfw)
        bfr[nf] = *(const i32x4*)(bp + ((uint)((c * nfw + nf) * 1024) + blane));
#pragma unroll
    for (int mf = 0; mf < MF; ++mf)
#pragma unroll
      for (int nf = 0; nf < NFW; ++nf)
        if (nf < nfw)
          acc[mf][nf] = __builtin_amdgcn_mfma_i32_16x16x64_i8(af[mf], bfr[nf],
                                                              acc[mf][nf], 0, 0, 0);
  }

  conv_epilogue<NFW, MF>(acc, nfw, lane, wave, mbase, yhb, stb, 256);
}

// ---------- 3x3 i8 MFMA conv, LDS-staged A tile (row-linear K) ----------
template <int CI, int KROWP, int COB, int WPEU>
__global__ __launch_bounds__(256, WPEU) void cstat9_kernel(
    const char* __restrict__ xin, const char* __restrict__ bp, int nft,
    double* __restrict__ stb, u16* __restrict__ yh) {
  constexpr int CPR = KROWP / 64;
  constexpr int NCH = 3 * CPR;
  constexpr int NFW = COB / 16;
  constexpr int MF = 2;
  constexpr int TILE = 6 * 34 * CI;
  constexpr int TV = TILE / 16;

  __shared__ __align__(16) char atile[TILE + 64];

  const int lane = threadIdx.x & 63;
  const int wave = threadIdx.x >> 6;
  const int mbase = blockIdx.x * 128 + wave * 32;

  {
    int p0 = blockIdx.x * 128;
    int n = p0 >> 10, h0 = (p0 & 1023) >> 5;
    const char* src = xin + (size_t)((n * 34 + h0) * 34) * CI;
    for (int s = threadIdx.x; s < TV; s += 256)
      *(uint4*)&atile[s * 16] = *(const uint4*)(src + (size_t)s * 16);
  }
  __syncthreads();

  uint albase[MF];
#pragma unroll
  for (int mf = 0; mf < MF; ++mf) {
    int lp = wave * 32 + mf * 16 + (lane & 15);
    albase[mf] = (uint)(((lp >> 5) * 34 + (lp & 31)) * CI);
  }
  const uint klane = (uint)(lane >> 4) * 16u;
  const uint blane = (uint)lane * 16u;

  i32x4 acc[MF][NFW];
#pragma unroll
  for (int i = 0; i < MF; ++i)
#pragma unroll
    for (int j = 0; j < NFW; ++j) acc[i][j] = {0, 0, 0, 0};

#pragma unroll 2
  for (int c = 0; c < NCH; ++c) {
    int rr = c / CPR, o = (c - rr * CPR) * 64;
    uint koff = (uint)(rr * 34 * CI + o);
    i32x4 af[MF];
#pragma unroll
    for (int mf = 0; mf < MF; ++mf)
      af[mf] = *(const i32x4*)&atile[albase[mf] + koff + klane];
    i32x4 bfr[NFW];
#pragma unroll
    for (int nf = 0; nf < NFW; ++nf)
      bfr[nf] = *(const i32x4*)(bp + ((uint)((c * nft + nf) * 1024) + blane));
#pragma unroll
    for (int mf = 0; mf < MF; ++mf)
#pragma unroll
      for (int nf = 0; nf < NFW; ++nf)
        acc[mf][nf] = __builtin_amdgcn_mfma_i32_16x16x64_i8(af[mf], bfr[nf],
                                                            acc[mf][nf], 0, 0, 0);
  }

  conv_epilogue<NFW, MF>(acc, NFW, lane, wave, mbase, yh, stb, 256);
}

// ---------- merged BN+ReLU for ALL out-branches -> f32 NCHW out ----------
struct BnPtrs { const float* g[4]; const float* be[4]; };

__global__ __launch_bounds__(256) void bnout_all_kernel(
    const u16* __restrict__ yh, const double* __restrict__ st, BnPtrs bp,
    float* __restrict__ out) {
  int co = blockIdx.y, chunk = blockIdx.x, tid = threadIdx.x;
  int br = (co < 64) ? 0 : (co < 192) ? 1 : (co < 224) ? 2 : 3;
  int lco = co - ((br == 0) ? 0 : (br == 1) ? 64 : (br == 2) ? 192 : 224);
  int yhoff = (br == 0) ? 0 : (br == 1) ? 208 : (br == 2) ? 368 : 176;
  int stoff = (br == 0) ? 0 : (br == 1) ? 2 * 256 * NREP
                         : (br == 2) ? 5 * 256 * NREP : 6 * 256 * NREP;
  const double* stb = st + stoff;
  double s1d = 0., s2d = 0.;
#pragma unroll
  for (int r = 0; r < NREP; ++r) {
    s1d += stb[r * 256 + 2 * lco];
    s2d += stb[r * 256 + 2 * lco + 1];
  }
  double m = s1d * (1.0 / PTOT);
  double v = s2d * (1.0 / PTOT) - m * m;
  double inv = 1.0 / sqrt(v + 1e-5);
  double c0d = (double)bp.g[br][lco] * inv;
  float c0 = (float)c0d;
  float c1 = (float)((double)bp.be[br][lco] - m * c0d);

  int p0 = chunk * 4096 + tid * 16;
  int n = p0 >> 10, hw = p0 & 1023;
  const u16* yp = yh + (size_t)(yhoff + lco) * PTOT + p0;
  float* op = out + (((size_t)(n * 256 + co)) << 10) + hw;
#pragma unroll
  for (int half = 0; half < 2; ++half) {
    u16x8 r = *(const u16x8*)(yp + half * 8);
    f32x4 a, b;
#pragma unroll
    for (int e = 0; e < 4; ++e) {
      a[e] = fmaxf(fmaf(bf2f(r[e]), c0, c1), 0.f);
      b[e] = fmaxf(fmaf(bf2f(r[e + 4]), c0, c1), 0.f);
    }
    *(f32x4*)(op + half * 8) = a;
    *(f32x4*)(op + half * 8 + 4) = b;
  }
}

// ---------- BN+ReLU+quantize -> padded NHWC int8 ----------
template <int CO, int COP>
__global__ __launch_bounds__(256) void bnqpad_kernel(const u16* __restrict__ yh,
                                                     const double* __restrict__ stb,
                                                     const float* __restrict__ g,
                                                     const float* __restrict__ be,
                                                     char* __restrict__ q) {
  __shared__ float2 cfl[CO];
  __shared__ __align__(16) char tile[64][COP + 16];
  const int t = threadIdx.x;
  if (t < CO) {
    double s1d = 0., s2d = 0.;
#pragma unroll
    for (int r = 0; r < NREP; ++r) {
      s1d += stb[r * 256 + 2 * t];
      s2d += stb[r * 256 + 2 * t + 1];
    }
    double m = s1d * (1.0 / PTOT);
    double v = s2d * (1.0 / PTOT) - m * m;
    double inv = 1.0 / sqrt(v + 1e-5);
    double c0 = (double)g[t] * inv;
    cfl[t] = make_float2((float)c0, (float)((double)be[t] - m * c0));
  }
  __syncthreads();
  int p0 = blockIdx.x * 64;
  int lane = t & 63, sub = t >> 6;
#pragma unroll
  for (int i = 0; i < COP / 4; ++i) {
    int co = sub + i * 4;
    float2 cc = cfl[co];
    float z = fmaxf(fmaf(bf2f(yh[(size_t)co * PTOT + p0 + lane]), cc.x, cc.y), 0.f);
    tile[lane][co] = (char)min((int)rintf(z * 128.f), 127);  // z>=0 after relu
  }
  __syncthreads();
  for (int chunk = t; chunk < 64 * (COP / 16); chunk += 256) {
    int px = chunk / (COP / 16), c16 = chunk % (COP / 16);
    int p = p0 + px;
    int n = p >> 10, hw = p & 1023, h = hw >> 5, w = hw & 31;
    size_t dst = (((size_t)n * 34 + h + 1) * 34 + (w + 1)) * COP + c16 * 16;
    *(uint4*)&q[dst] = *(const uint4*)&tile[px][c16 * 16];
  }
}

extern "C" void kernel_launch(void* const* d_in, const int* in_sizes, int n_in,
                              void* d_out, int out_size, void* d_ws, size_t ws_size,
                              hipStream_t stream) {
  const float* x = (const float*)d_in[0];
  float* out = (float*)d_out;
  char* ws = (char*)d_ws;

  // ---- workspace layout (total 155,599,872 B; <=168 MB known-good) ----
  if (ws_size < 155599872ull) return;
  char* xq  = ws;                            // [PTOT][192] i8        = 25,165,824 B
  char* xpq = ws + 25165824ull;              // pooled [PTOT][192] i8 (dies after cstat1x1)
  char* q2a = xpq;                           // reuse: [128][34][34][96] +slack
  char* q3a = ws + 39371008ull;              // [128][34][34][16] +256
  char* q3b = ws + 41738752ull;              // [128][34][34][32] +256 (< 50,331,648)
  u16* yh   = (u16*)(ws + 50331648ull);      // [400][PTOT] bf16     = 104,857,600 B
  // yh slices (channel offsets): b1 0, b2a 64, b3a 160, b4 176, b2b 208,
  //                              b3b 336, b3c 368
  char* bpk = ws + 155189248ull;             // packed i8 weights        181,248 B
  double* st = (double*)(ws + 155370496ull); // 7 x NREP x 256 doubles   229,376 B

  hipMemsetAsync(st, 0, 7 * NREP * 256 * 8, stream);

  WPtrs wp;
  const int widx[7] = {1, 5, 9, 13, 17, 21, 25};
  for (int i = 0; i < 7; ++i) wp.p[i] = (const float*)d_in[widx[i]];
  wpack_kernel<<<708, 256, 0, stream>>>(wp, bpk);

  quantx_kernel<<<dim3(16, 3, 128), 256, 0, stream>>>(x, xq);
  pool_kernel<<<6144, 256, 0, stream>>>(xq, xpq);

  double* stB[7];
  for (int b = 0; b < 7; ++b) stB[b] = st + (size_t)b * NREP * 256;

  // ---- merged 1x1 convs: b1 / b2a / b3a / b4 in one launch ----
  cstat1x1_kernel<<<dim3(1024, 4), 256, 0, stream>>>(xq, xpq, bpk, st, yh);

  // zero borders of padded q buffers (q2a aliases xpq, now dead)
  border_kernel<<<dim3(128, 3), 256, 0, stream>>>(q2a, q3a, q3b);

  // ---- b2a apply -> q2a; then b2b conv ----
  bnqpad_kernel<96, 96><<<2048, 256, 0, stream>>>(yh + (size_t)64 * PTOT, stB[1],
                                                  (const float*)d_in[7],
                                                  (const float*)d_in[8], q2a);
  cstat9_kernel<96, 320, 128, 3><<<1024, 256, 0, stream>>>(
      q2a, bpk + 30720, 8, stB[2], yh + (size_t)208 * PTOT);

  // ---- b3 chain: b3a apply -> b3b conv -> b3b apply -> b3c conv ----
  bnqpad_kernel<16, 16><<<2048, 256, 0, stream>>>(yh + (size_t)160 * PTOT, stB[3],
                                                  (const float*)d_in[15],
                                                  (const float*)d_in[16], q3a);
  cstat9_kernel<16, 64, 32, 4><<<1024, 256, 0, stream>>>(
      q3a, bpk + 156672, 2, stB[4], yh + (size_t)336 * PTOT);
  bnqpad_kernel<32, 32><<<2048, 256, 0, stream>>>(yh + (size_t)336 * PTOT, stB[4],
                                                  (const float*)d_in[19],
                                                  (const float*)d_in[20], q3b);
  cstat9_kernel<32, 128, 32, 4><<<1024, 256, 0, stream>>>(
      q3b, bpk + 162816, 2, stB[5], yh + (size_t)368 * PTOT);

  // ---- single merged BN+ReLU for all 256 output channels ----
  BnPtrs bp;
  bp.g[0] = (const float*)d_in[3];  bp.be[0] = (const float*)d_in[4];   // b1
  bp.g[1] = (const float*)d_in[11]; bp.be[1] = (const float*)d_in[12];  // b2b
  bp.g[2] = (const float*)d_in[23]; bp.be[2] = (const float*)d_in[24];  // b3c
  bp.g[3] = (const float*)d_in[27]; bp.be[3] = (const float*)d_in[28];  // b4
  bnout_all_kernel<<<dim3(32, 256), 256, 0, stream>>>(yh, st, bp, out);
}

// Round 14
// 206.894 us; speedup vs baseline: 1.2063x; 1.0420x over previous
//
#include <hip/hip_runtime.h>

typedef unsigned short u16;
typedef unsigned int u32;
typedef __attribute__((ext_vector_type(4))) int i32x4;
typedef __attribute__((ext_vector_type(4))) float f32x4;
typedef __attribute__((ext_vector_type(4))) u16 u16x4;
typedef __attribute__((ext_vector_type(8))) u16 u16x8;

#define PTOT 131072   // 128 images * 32*32 pixels
#define NREP 16       // stat accumulator replicas (atomic de-contention)

// ---------- helpers ----------
static __device__ __forceinline__ int qi8(float v) {  // round-half-even, clip +-127
  int q = (int)rintf(v * 128.f);
  return max(-127, min(127, q));
}
static __device__ __forceinline__ u16 bf_rne(float v) { // round-nearest-even bf16
  u32 u = __float_as_uint(v);
  u += 0x7fffu + ((u >> 16) & 1u);
  return (u16)(u >> 16);
}
static __device__ __forceinline__ float bf2f(u16 v) {
  return __uint_as_float((u32)v << 16);
}

// ---------- weight quantize + i8 MFMA fragment packing (row-linear K) ----------
struct WPtrs { const float* p[7]; };

__global__ void wpack_kernel(WPtrs wp, char* __restrict__ o) {
  // {byte_off, CIr, KROWP, KH, Co}   (len = NCH*NF*1024)
  static const int S[7][5] = {
      {0,      192, 192, 1, 64},   // b1   NCH=3 NF=4  12288
      {12288,  192, 192, 1, 96},   // b2a  NCH=3 NF=6  18432
      {30720,  96,  320, 3, 128},  // b2b  NCH=15 NF=8 122880
      {153600, 192, 192, 1, 16},   // b3a  NCH=3 NF=1  3072
      {156672, 16,  64,  3, 32},   // b3b  NCH=3 NF=2  6144
      {162816, 32,  128, 3, 32},   // b3c  NCH=6 NF=2  12288
      {175104, 192, 192, 1, 32},   // b4   NCH=3 NF=2  6144
  };
  int idx = blockIdx.x * 256 + threadIdx.x;
  if (idx >= 181248) return;
  int s = 0;
#pragma unroll
  for (int i = 1; i < 7; ++i)
    if (idx >= S[i][0]) s = i;
  int local = idx - S[s][0];
  int CIr = S[s][1], KROWP = S[s][2], KH = S[s][3], Co = S[s][4];
  int j = local & 15, lane = (local >> 4) & 63, f = local >> 10;
  int NF = Co >> 4;
  int c = f / NF, nf = f - c * NF;
  int co = nf * 16 + (lane & 15);
  int k = c * 64 + ((lane >> 4) << 4) + j;
  int r = k / KROWP, kk = k - r * KROWP;
  char val = 0;
  if (kk < 3 * CIr || KH == 1) {
    int kw = (KH == 1) ? 0 : (kk / CIr);
    int ci = (KH == 1) ? kk : (kk - kw * CIr);
    val = (char)qi8(wp.p[s][(((size_t)co * CIr + ci) * KH + r) * KH + kw]);
  }
  o[idx] = val;
}

// ---------- quantize x: NCHW f32 -> NHWC int8 ----------
__global__ __launch_bounds__(256) void quantx_kernel(const float* __restrict__ x,
                                                     char* __restrict__ xq) {
  __shared__ __align__(16) char tile[64][80];
  int n = blockIdx.z, hwb = blockIdx.x * 64, cb = blockIdx.y * 64;
  int lane = threadIdx.x & 63, sub = threadIdx.x >> 6;
#pragma unroll
  for (int i = 0; i < 16; ++i) {
    int c = sub + i * 4;
    float v = x[(((size_t)n * 192 + cb + c) << 10) + hwb + lane];
    tile[lane][c] = (char)qi8(v);
  }
  __syncthreads();
  int t = threadIdx.x, px = t >> 2, c16 = t & 3;
  uint4 v = *(const uint4*)&tile[px][c16 * 16];
  *(uint4*)&xq[(((size_t)n << 10) + hwb + px) * 192 + cb + c16 * 16] = v;
}

// ---------- maxpool 3x3 s1 p1 on int8 NHWC ----------
__global__ __launch_bounds__(256) void pool_kernel(const char* __restrict__ xq,
                                                   char* __restrict__ xpq) {
  int idx = blockIdx.x * 256 + threadIdx.x;
  int c16 = idx % 12;
  int p = idx / 12;
  int n = p >> 10, hw = p & 1023, h = hw >> 5, w = hw & 31;
  int m[16];
#pragma unroll
  for (int j = 0; j < 16; ++j) m[j] = -127;
  for (int dh = -1; dh <= 1; ++dh) {
    int hh = h + dh; if (hh < 0 || hh > 31) continue;
    for (int dw = -1; dw <= 1; ++dw) {
      int ww = w + dw; if (ww < 0 || ww > 31) continue;
      uint4 v = *(const uint4*)&xq[((((size_t)n << 5) + hh) * 32 + ww) * 192 + c16 * 16];
      const char* bb = reinterpret_cast<const char*>(&v);
#pragma unroll
      for (int t = 0; t < 16; ++t) {
        int b = (int)bb[t];
        m[t] = b > m[t] ? b : m[t];
      }
    }
  }
  uint4 o;
  char* ob = reinterpret_cast<char*>(&o);
#pragma unroll
  for (int t = 0; t < 16; ++t) ob[t] = (char)m[t];
  *(uint4*)&xpq[(size_t)p * 192 + c16 * 16] = o;
}

// ---------- shared conv epilogue (runtime nfw guard) ----------
template <int NFW, int MF>
static __device__ __forceinline__ void conv_epilogue(
    i32x4 (&acc)[MF][NFW], int nfw, int lane, int wave, int mbase,
    u16* __restrict__ yh, double* __restrict__ stb, int ststride) {
  float yv[MF][NFW][4];
#pragma unroll
  for (int mf = 0; mf < MF; ++mf)
#pragma unroll
    for (int nf = 0; nf < NFW; ++nf)
      if (nf < nfw) {
        int col = nf * 16 + (lane & 15);
        int pix = mbase + mf * 16 + ((lane >> 4) << 2);
        u16x4 o;
#pragma unroll
        for (int r = 0; r < 4; ++r) {
          float v = (float)acc[mf][nf][r] * 6.103515625e-05f;  // 2^-14 (exact)
          yv[mf][nf][r] = v;
          o[r] = bf_rne(v);
        }
        *(u16x4*)&yh[(size_t)col * PTOT + pix] = o;
      }

  float s1[NFW], s2[NFW];
#pragma unroll
  for (int nf = 0; nf < NFW; ++nf) { s1[nf] = 0.f; s2[nf] = 0.f; }
#pragma unroll
  for (int mf = 0; mf < MF; ++mf)
#pragma unroll
    for (int nf = 0; nf < NFW; ++nf)
      if (nf < nfw)
#pragma unroll
        for (int r = 0; r < 4; ++r) {
          float v = yv[mf][nf][r];
          s1[nf] += v;
          s2[nf] += v * v;
        }
#pragma unroll
  for (int m = 16; m <= 32; m <<= 1)
#pragma unroll
    for (int nf = 0; nf < NFW; ++nf) {
      s1[nf] += __shfl_xor(s1[nf], m);
      s2[nf] += __shfl_xor(s2[nf], m);
    }
  __shared__ float red[4][NFW][16][2];
  if (lane < 16)
#pragma unroll
    for (int nf = 0; nf < NFW; ++nf) {
      red[wave][nf][lane][0] = s1[nf];
      red[wave][nf][lane][1] = s2[nf];
    }
  __syncthreads();
  const int t = threadIdx.x;
  if (t < 16 * nfw) {
    int nf = t >> 4, l = t & 15;
    float a = red[0][nf][l][0] + red[1][nf][l][0] + red[2][nf][l][0] + red[3][nf][l][0];
    float b = red[0][nf][l][1] + red[1][nf][l][1] + red[2][nf][l][1] + red[3][nf][l][1];
    int rep = blockIdx.x & (NREP - 1);
    atomicAdd(&stb[rep * ststride + 2 * t], (double)a);
    atomicAdd(&stb[rep * ststride + 2 * t + 1], (double)b);
  }
}

// ---------- merged 1x1 convs: blockIdx.y selects branch {b1,b2a,b3a,b4} ----------
__global__ __launch_bounds__(256, 4) void cstat1x1_kernel(
    const char* __restrict__ xq, const char* __restrict__ xpq,
    const char* __restrict__ bpk, double* __restrict__ st, u16* __restrict__ yh) {
  constexpr int NFW = 6;
  constexpr int MF = 2;
  const int b = blockIdx.y;  // uniform
  const int nfw = (b == 0) ? 4 : (b == 1) ? 6 : (b == 2) ? 1 : 2;
  const int bpo = (b == 0) ? 0 : (b == 1) ? 12288 : (b == 2) ? 153600 : 175104;
  const int sto = (b == 0) ? 0 : (b == 1) ? 256 * NREP
                           : (b == 2) ? 3 * 256 * NREP : 6 * 256 * NREP;
  const int yho = (b == 0) ? 0 : (b == 1) ? 64 : (b == 2) ? 160 : 176;
  const char* xin = (b == 3) ? xpq : xq;
  const char* bp = bpk + bpo;
  double* stb = st + sto;
  u16* yhb = yh + (size_t)yho * PTOT;

  const int lane = threadIdx.x & 63;
  const int wave = threadIdx.x >> 6;
  const int mbase = blockIdx.x * 128 + wave * 32;

  uint abase[MF];
#pragma unroll
  for (int mf = 0; mf < MF; ++mf)
    abase[mf] = (uint)(mbase + mf * 16 + (lane & 15)) * 192u;
  const uint klane = (uint)(lane >> 4) * 16u;
  const uint blane = (uint)lane * 16u;

  i32x4 acc[MF][NFW];
#pragma unroll
  for (int i = 0; i < MF; ++i)
#pragma unroll
    for (int j = 0; j < NFW; ++j) acc[i][j] = {0, 0, 0, 0};

#pragma unroll
  for (int c = 0; c < 3; ++c) {
    i32x4 af[MF];
#pragma unroll
    for (int mf = 0; mf < MF; ++mf)
      af[mf] = *(const i32x4*)(xin + (abase[mf] + (uint)c * 64u + klane));
    i32x4 bfr[NFW];
#pragma unroll
    for (int nf = 0; nf < NFW; ++nf)
      if (nf < nfw)
        bfr[nf] = *(const i32x4*)(bp + ((uint)((c * nfw + nf) * 1024) + blane));
#pragma unroll
    for (int mf = 0; mf < MF; ++mf)
#pragma unroll
      for (int nf = 0; nf < NFW; ++nf)
        if (nf < nfw)
          acc[mf][nf] = __builtin_amdgcn_mfma_i32_16x16x64_i8(af[mf], bfr[nf],
                                                              acc[mf][nf], 0, 0, 0);
  }

  conv_epilogue<NFW, MF>(acc, nfw, lane, wave, mbase, yhb, stb, 256);
}

// ---------- 3x3 conv with fused input qstage (yh_in + stats -> LDS i8 tile) ----------
// Block = 128 px = 4 rows of one image. Stages padded rows h0-1..h0+4 into a
// zeroed [6][34][CI] i8 LDS tile, applying producer BN+ReLU+quantize on the fly
// (coefs from producer stats -> identical values to the old bnqpad path).
// Row-tail K-pad reads hit in-tile garbage * zero-weight = exact 0. Borders are
// the pre-zeroed cells. Then row-linear-K i8 MFMA conv as before.
template <int CI, int KROWP, int COB, int WPEU>
__global__ __launch_bounds__(256, WPEU) void cstat9q_kernel(
    const u16* __restrict__ yhin, const double* __restrict__ stp,
    const float* __restrict__ gp, const float* __restrict__ bep,
    const char* __restrict__ bp, int nft,
    double* __restrict__ stb, u16* __restrict__ yh) {
  constexpr int CPR = KROWP / 64;
  constexpr int NCH = 3 * CPR;
  constexpr int NFW = COB / 16;
  constexpr int MF = 2;
  constexpr int TILE = 6 * 34 * CI;

  __shared__ __align__(16) char atile[TILE + 64];
  __shared__ float2 cfl[CI];

  const int tid = threadIdx.x;

  // producer BN coefs (stats complete: producer kernel retired)
  if (tid < CI) {
    double s1d = 0., s2d = 0.;
#pragma unroll
    for (int r = 0; r < NREP; ++r) {
      s1d += stp[r * 256 + 2 * tid];
      s2d += stp[r * 256 + 2 * tid + 1];
    }
    double m = s1d * (1.0 / PTOT);
    double v = s2d * (1.0 / PTOT) - m * m;
    double inv = 1.0 / sqrt(v + 1e-5);
    double c0 = (double)gp[tid] * inv;
    cfl[tid] = make_float2((float)c0, (float)((double)bep[tid] - m * c0));
  }
  // zero tile (borders + slack)
  {
    uint4 z = {0, 0, 0, 0};
    for (int s = tid * 16; s < TILE + 64; s += 4096) *(uint4*)&atile[s] = z;
  }
  __syncthreads();

  // qstage: image rows h0-1 .. h0+4 -> padded tile rows 0..5, cols 1..32
  const int p0 = blockIdx.x * 128;
  const int n = p0 >> 10, h0 = (p0 & 1023) >> 5;
  for (int task = tid; task < CI * 6; task += 256) {
    int co = task / 6, rr = task - co * 6;
    int irow = h0 - 1 + rr;
    if (irow < 0 || irow > 31) continue;
    const u16* src = yhin + (size_t)co * PTOT + (n << 10) + (irow << 5);
    float2 cc = cfl[co];
    char* dst = &atile[(rr * 34 + 1) * CI + co];
#pragma unroll
    for (int w8 = 0; w8 < 4; ++w8) {
      u16x8 v = *(const u16x8*)(src + w8 * 8);
#pragma unroll
      for (int e = 0; e < 8; ++e) {
        float z = fmaxf(fmaf(bf2f(v[e]), cc.x, cc.y), 0.f);
        dst[(w8 * 8 + e) * CI] = (char)min((int)rintf(z * 128.f), 127);
      }
    }
  }
  __syncthreads();

  // ---- conv (row-linear K) ----
  const int lane = tid & 63;
  const int wave = tid >> 6;
  const int mbase = blockIdx.x * 128 + wave * 32;

  uint albase[MF];
#pragma unroll
  for (int mf = 0; mf < MF; ++mf) {
    int lp = wave * 32 + mf * 16 + (lane & 15);  // local pixel in [0,128)
    albase[mf] = (uint)((((lp >> 5) + 1) * 34 + 1 + (lp & 31)) * CI);
  }
  const uint klane = (uint)(lane >> 4) * 16u;
  const uint blane = (uint)lane * 16u;

  i32x4 acc[MF][NFW];
#pragma unroll
  for (int i = 0; i < MF; ++i)
#pragma unroll
    for (int j = 0; j < NFW; ++j) acc[i][j] = {0, 0, 0, 0};

#pragma unroll 2
  for (int c = 0; c < NCH; ++c) {
    int rr = c / CPR, o = (c - rr * CPR) * 64;
    uint koff = (uint)((rr - 1) * 34 * CI + o - CI);  // tap(0,0) = row-1,col-1
    i32x4 af[MF];
#pragma unroll
    for (int mf = 0; mf < MF; ++mf)
      af[mf] = *(const i32x4*)&atile[albase[mf] + koff + klane];
    i32x4 bfr[NFW];
#pragma unroll
    for (int nf = 0; nf < NFW; ++nf)
      bfr[nf] = *(const i32x4*)(bp + ((uint)((c * nft + nf) * 1024) + blane));
#pragma unroll
    for (int mf = 0; mf < MF; ++mf)
#pragma unroll
      for (int nf = 0; nf < NFW; ++nf)
        acc[mf][nf] = __builtin_amdgcn_mfma_i32_16x16x64_i8(af[mf], bfr[nf],
                                                            acc[mf][nf], 0, 0, 0);
  }

  conv_epilogue<NFW, MF>(acc, NFW, lane, wave, mbase, yh, stb, 256);
}

// ---------- merged BN+ReLU for ALL out-branches -> f32 NCHW out ----------
struct BnPtrs { const float* g[4]; const float* be[4]; };

__global__ __launch_bounds__(256) void bnout_all_kernel(
    const u16* __restrict__ yh, const double* __restrict__ st, BnPtrs bp,
    float* __restrict__ out) {
  int co = blockIdx.y, chunk = blockIdx.x, tid = threadIdx.x;
  int br = (co < 64) ? 0 : (co < 192) ? 1 : (co < 224) ? 2 : 3;
  int lco = co - ((br == 0) ? 0 : (br == 1) ? 64 : (br == 2) ? 192 : 224);
  int yhoff = (br == 0) ? 0 : (br == 1) ? 208 : (br == 2) ? 368 : 176;
  int stoff = (br == 0) ? 0 : (br == 1) ? 2 * 256 * NREP
                         : (br == 2) ? 5 * 256 * NREP : 6 * 256 * NREP;
  const double* stb = st + stoff;
  double s1d = 0., s2d = 0.;
#pragma unroll
  for (int r = 0; r < NREP; ++r) {
    s1d += stb[r * 256 + 2 * lco];
    s2d += stb[r * 256 + 2 * lco + 1];
  }
  double m = s1d * (1.0 / PTOT);
  double v = s2d * (1.0 / PTOT) - m * m;
  double inv = 1.0 / sqrt(v + 1e-5);
  double c0d = (double)bp.g[br][lco] * inv;
  float c0 = (float)c0d;
  float c1 = (float)((double)bp.be[br][lco] - m * c0d);

  int p0 = chunk * 4096 + tid * 16;
  int n = p0 >> 10, hw = p0 & 1023;
  const u16* yp = yh + (size_t)(yhoff + lco) * PTOT + p0;
  float* op = out + (((size_t)(n * 256 + co)) << 10) + hw;
#pragma unroll
  for (int half = 0; half < 2; ++half) {
    u16x8 r = *(const u16x8*)(yp + half * 8);
    f32x4 a, b;
#pragma unroll
    for (int e = 0; e < 4; ++e) {
      a[e] = fmaxf(fmaf(bf2f(r[e]), c0, c1), 0.f);
      b[e] = fmaxf(fmaf(bf2f(r[e + 4]), c0, c1), 0.f);
    }
    *(f32x4*)(op + half * 8) = a;
    *(f32x4*)(op + half * 8 + 4) = b;
  }
}

extern "C" void kernel_launch(void* const* d_in, const int* in_sizes, int n_in,
                              void* d_out, int out_size, void* d_ws, size_t ws_size,
                              hipStream_t stream) {
  const float* x = (const float*)d_in[0];
  float* out = (float*)d_out;
  char* ws = (char*)d_ws;

  // ---- workspace layout (total 155,599,872 B) ----
  if (ws_size < 155599872ull) return;
  char* xq  = ws;                            // [PTOT][192] i8        = 25,165,824 B
  char* xpq = ws + 25165824ull;              // pooled [PTOT][192] i8 = 25,165,824 B
  u16* yh   = (u16*)(ws + 50331648ull);      // [400][PTOT] bf16     = 104,857,600 B
  // yh slices (channel offsets): b1 0, b2a 64, b3a 160, b4 176, b2b 208,
  //                              b3b 336, b3c 368
  char* bpk = ws + 155189248ull;             // packed i8 weights        181,248 B
  double* st = (double*)(ws + 155370496ull); // 7 x NREP x 256 doubles   229,376 B

  hipMemsetAsync(st, 0, 7 * NREP * 256 * 8, stream);

  WPtrs wp;
  const int widx[7] = {1, 5, 9, 13, 17, 21, 25};
  for (int i = 0; i < 7; ++i) wp.p[i] = (const float*)d_in[widx[i]];
  wpack_kernel<<<708, 256, 0, stream>>>(wp, bpk);

  quantx_kernel<<<dim3(16, 3, 128), 256, 0, stream>>>(x, xq);
  pool_kernel<<<6144, 256, 0, stream>>>(xq, xpq);

  double* stB[7];
  for (int b = 0; b < 7; ++b) stB[b] = st + (size_t)b * NREP * 256;

  // ---- merged 1x1 convs: b1 / b2a / b3a / b4 in one launch ----
  cstat1x1_kernel<<<dim3(1024, 4), 256, 0, stream>>>(xq, xpq, bpk, st, yh);

  // ---- b2b: qstage(b2a yh + stats) -> 3x3 96->128 ----
  cstat9q_kernel<96, 320, 128, 3><<<1024, 256, 0, stream>>>(
      yh + (size_t)64 * PTOT, stB[1], (const float*)d_in[7], (const float*)d_in[8],
      bpk + 30720, 8, stB[2], yh + (size_t)208 * PTOT);

  // ---- b3b: qstage(b3a yh + stats) -> 3x3 16->32 ----
  cstat9q_kernel<16, 64, 32, 4><<<1024, 256, 0, stream>>>(
      yh + (size_t)160 * PTOT, stB[3], (const float*)d_in[15], (const float*)d_in[16],
      bpk + 156672, 2, stB[4], yh + (size_t)336 * PTOT);

  // ---- b3c: qstage(b3b yh + stats) -> 3x3 32->32 ----
  cstat9q_kernel<32, 128, 32, 4><<<1024, 256, 0, stream>>>(
      yh + (size_t)336 * PTOT, stB[4], (const float*)d_in[19], (const float*)d_in[20],
      bpk + 162816, 2, stB[5], yh + (size_t)368 * PTOT);

  // ---- single merged BN+ReLU for all 256 output channels ----
  BnPtrs bp;
  bp.g[0] = (const float*)d_in[3];  bp.be[0] = (const float*)d_in[4];   // b1
  bp.g[1] = (const float*)d_in[11]; bp.be[1] = (const float*)d_in[12];  // b2b
  bp.g[2] = (const float*)d_in[23]; bp.be[2] = (const float*)d_in[24];  // b3c
  bp.g[3] = (const float*)d_in[27]; bp.be[3] = (const float*)d_in[28];  // b4
  bnout_all_kernel<<<dim3(32, 256), 256, 0, stream>>>(yh, st, bp, out);
}

// Round 15
// 193.586 us; speedup vs baseline: 1.2892x; 1.0687x over previous
//
#include <hip/hip_runtime.h>

typedef unsigned short u16;
typedef unsigned int u32;
typedef __attribute__((ext_vector_type(4))) int i32x4;
typedef __attribute__((ext_vector_type(4))) float f32x4;
typedef __attribute__((ext_vector_type(4))) u16 u16x4;
typedef __attribute__((ext_vector_type(8))) u16 u16x8;

#define PTOT 131072   // 128 images * 32*32 pixels
#define NREP 16       // stat accumulator replicas (atomic de-contention)

// ---------- helpers ----------
static __device__ __forceinline__ int qi8(float v) {  // round-half-even, clip +-127
  int q = (int)rintf(v * 128.f);
  return max(-127, min(127, q));
}
static __device__ __forceinline__ u16 bf_rne(float v) { // round-nearest-even bf16
  u32 u = __float_as_uint(v);
  u += 0x7fffu + ((u >> 16) & 1u);
  return (u16)(u >> 16);
}
static __device__ __forceinline__ float bf2f(u16 v) {
  return __uint_as_float((u32)v << 16);
}

// ---------- weight quantize + i8 MFMA fragment packing (row-linear K) ----------
struct WPtrs { const float* p[7]; };

__global__ void wpack_kernel(WPtrs wp, char* __restrict__ o) {
  // {byte_off, CIr, KROWP, KH, Co}   (len = NCH*NF*1024)
  static const int S[7][5] = {
      {0,      192, 192, 1, 64},   // b1   NCH=3 NF=4  12288
      {12288,  192, 192, 1, 96},   // b2a  NCH=3 NF=6  18432
      {30720,  96,  320, 3, 128},  // b2b  NCH=15 NF=8 122880
      {153600, 192, 192, 1, 16},   // b3a  NCH=3 NF=1  3072
      {156672, 16,  64,  3, 32},   // b3b  NCH=3 NF=2  6144
      {162816, 32,  128, 3, 32},   // b3c  NCH=6 NF=2  12288
      {175104, 192, 192, 1, 32},   // b4   NCH=3 NF=2  6144
  };
  int idx = blockIdx.x * 256 + threadIdx.x;
  if (idx >= 181248) return;
  int s = 0;
#pragma unroll
  for (int i = 1; i < 7; ++i)
    if (idx >= S[i][0]) s = i;
  int local = idx - S[s][0];
  int CIr = S[s][1], KROWP = S[s][2], KH = S[s][3], Co = S[s][4];
  int j = local & 15, lane = (local >> 4) & 63, f = local >> 10;
  int NF = Co >> 4;
  int c = f / NF, nf = f - c * NF;
  int co = nf * 16 + (lane & 15);
  int k = c * 64 + ((lane >> 4) << 4) + j;
  int r = k / KROWP, kk = k - r * KROWP;
  char val = 0;
  if (kk < 3 * CIr || KH == 1) {
    int kw = (KH == 1) ? 0 : (kk / CIr);
    int ci = (KH == 1) ? kk : (kk - kw * CIr);
    val = (char)qi8(wp.p[s][(((size_t)co * CIr + ci) * KH + r) * KH + kw]);
  }
  o[idx] = val;
}

// ---------- quantize x: NCHW f32 -> NHWC int8 ----------
__global__ __launch_bounds__(256) void quantx_kernel(const float* __restrict__ x,
                                                     char* __restrict__ xq) {
  __shared__ __align__(16) char tile[64][80];
  int n = blockIdx.z, hwb = blockIdx.x * 64, cb = blockIdx.y * 64;
  int lane = threadIdx.x & 63, sub = threadIdx.x >> 6;
#pragma unroll
  for (int i = 0; i < 16; ++i) {
    int c = sub + i * 4;
    float v = x[(((size_t)n * 192 + cb + c) << 10) + hwb + lane];
    tile[lane][c] = (char)qi8(v);
  }
  __syncthreads();
  int t = threadIdx.x, px = t >> 2, c16 = t & 3;
  uint4 v = *(const uint4*)&tile[px][c16 * 16];
  *(uint4*)&xq[(((size_t)n << 10) + hwb + px) * 192 + cb + c16 * 16] = v;
}

// ---------- maxpool 3x3 s1 p1 on int8 NHWC ----------
__global__ __launch_bounds__(256) void pool_kernel(const char* __restrict__ xq,
                                                   char* __restrict__ xpq) {
  int idx = blockIdx.x * 256 + threadIdx.x;
  int c16 = idx % 12;
  int p = idx / 12;
  int n = p >> 10, hw = p & 1023, h = hw >> 5, w = hw & 31;
  int m[16];
#pragma unroll
  for (int j = 0; j < 16; ++j) m[j] = -127;
  for (int dh = -1; dh <= 1; ++dh) {
    int hh = h + dh; if (hh < 0 || hh > 31) continue;
    for (int dw = -1; dw <= 1; ++dw) {
      int ww = w + dw; if (ww < 0 || ww > 31) continue;
      uint4 v = *(const uint4*)&xq[((((size_t)n << 5) + hh) * 32 + ww) * 192 + c16 * 16];
      const char* bb = reinterpret_cast<const char*>(&v);
#pragma unroll
      for (int t = 0; t < 16; ++t) {
        int b = (int)bb[t];
        m[t] = b > m[t] ? b : m[t];
      }
    }
  }
  uint4 o;
  char* ob = reinterpret_cast<char*>(&o);
#pragma unroll
  for (int t = 0; t < 16; ++t) ob[t] = (char)m[t];
  *(uint4*)&xpq[(size_t)p * 192 + c16 * 16] = o;
}

// ---------- shared conv epilogue (runtime nfw guard) ----------
template <int NFW, int MF>
static __device__ __forceinline__ void conv_epilogue(
    i32x4 (&acc)[MF][NFW], int nfw, int lane, int wave, int mbase,
    u16* __restrict__ yh, double* __restrict__ stb, int ststride) {
  float yv[MF][NFW][4];
#pragma unroll
  for (int mf = 0; mf < MF; ++mf)
#pragma unroll
    for (int nf = 0; nf < NFW; ++nf)
      if (nf < nfw) {
        int col = nf * 16 + (lane & 15);
        int pix = mbase + mf * 16 + ((lane >> 4) << 2);
        u16x4 o;
#pragma unroll
        for (int r = 0; r < 4; ++r) {
          float v = (float)acc[mf][nf][r] * 6.103515625e-05f;  // 2^-14 (exact)
          yv[mf][nf][r] = v;
          o[r] = bf_rne(v);
        }
        *(u16x4*)&yh[(size_t)col * PTOT + pix] = o;
      }

  float s1[NFW], s2[NFW];
#pragma unroll
  for (int nf = 0; nf < NFW; ++nf) { s1[nf] = 0.f; s2[nf] = 0.f; }
#pragma unroll
  for (int mf = 0; mf < MF; ++mf)
#pragma unroll
    for (int nf = 0; nf < NFW; ++nf)
      if (nf < nfw)
#pragma unroll
        for (int r = 0; r < 4; ++r) {
          float v = yv[mf][nf][r];
          s1[nf] += v;
          s2[nf] += v * v;
        }
#pragma unroll
  for (int m = 16; m <= 32; m <<= 1)
#pragma unroll
    for (int nf = 0; nf < NFW; ++nf) {
      s1[nf] += __shfl_xor(s1[nf], m);
      s2[nf] += __shfl_xor(s2[nf], m);
    }
  __shared__ float red[4][NFW][16][2];
  if (lane < 16)
#pragma unroll
    for (int nf = 0; nf < NFW; ++nf) {
      red[wave][nf][lane][0] = s1[nf];
      red[wave][nf][lane][1] = s2[nf];
    }
  __syncthreads();
  const int t = threadIdx.x;
  if (t < 16 * nfw) {
    int nf = t >> 4, l = t & 15;
    float a = red[0][nf][l][0] + red[1][nf][l][0] + red[2][nf][l][0] + red[3][nf][l][0];
    float b = red[0][nf][l][1] + red[1][nf][l][1] + red[2][nf][l][1] + red[3][nf][l][1];
    int rep = blockIdx.x & (NREP - 1);
    atomicAdd(&stb[rep * ststride + 2 * t], (double)a);
    atomicAdd(&stb[rep * ststride + 2 * t + 1], (double)b);
  }
}

// ---------- merged 1x1 convs: blockIdx.y selects branch; whole-B in LDS ----------
__global__ __launch_bounds__(256, 4) void cstat1x1_kernel(
    const char* __restrict__ xq, const char* __restrict__ xpq,
    const char* __restrict__ bpk, double* __restrict__ st, u16* __restrict__ yh) {
  constexpr int NFW = 6;
  constexpr int MF = 2;
  __shared__ __align__(16) char btile[18432];  // max branch B (b2a: 3*6 KB)

  const int b = blockIdx.y;  // uniform
  const int nfw = (b == 0) ? 4 : (b == 1) ? 6 : (b == 2) ? 1 : 2;
  const int bpo = (b == 0) ? 0 : (b == 1) ? 12288 : (b == 2) ? 153600 : 175104;
  const int sto = (b == 0) ? 0 : (b == 1) ? 256 * NREP
                           : (b == 2) ? 3 * 256 * NREP : 6 * 256 * NREP;
  const int yho = (b == 0) ? 0 : (b == 1) ? 64 : (b == 2) ? 160 : 176;
  const char* xin = (b == 3) ? xpq : xq;
  const char* bp = bpk + bpo;
  double* stb = st + sto;
  u16* yhb = yh + (size_t)yho * PTOT;

  const int tid = threadIdx.x;
  const int bsz = nfw * 3 * 1024;
  for (int s = tid * 16; s < bsz; s += 4096)
    *(uint4*)&btile[s] = *(const uint4*)(bp + s);
  __syncthreads();

  const int lane = tid & 63;
  const int wave = tid >> 6;
  const int mbase = blockIdx.x * 128 + wave * 32;

  uint abase[MF];
#pragma unroll
  for (int mf = 0; mf < MF; ++mf)
    abase[mf] = (uint)(mbase + mf * 16 + (lane & 15)) * 192u;
  const uint klane = (uint)(lane >> 4) * 16u;
  const uint blane = (uint)lane * 16u;

  i32x4 acc[MF][NFW];
#pragma unroll
  for (int i = 0; i < MF; ++i)
#pragma unroll
    for (int j = 0; j < NFW; ++j) acc[i][j] = {0, 0, 0, 0};

#pragma unroll
  for (int c = 0; c < 3; ++c) {
    i32x4 af[MF];
#pragma unroll
    for (int mf = 0; mf < MF; ++mf)
      af[mf] = *(const i32x4*)(xin + (abase[mf] + (uint)c * 64u + klane));
    i32x4 bfr[NFW];
#pragma unroll
    for (int nf = 0; nf < NFW; ++nf)
      if (nf < nfw)
        bfr[nf] = *(const i32x4*)&btile[(uint)((c * nfw + nf) * 1024) + blane];
#pragma unroll
    for (int mf = 0; mf < MF; ++mf)
#pragma unroll
      for (int nf = 0; nf < NFW; ++nf)
        if (nf < nfw)
          acc[mf][nf] = __builtin_amdgcn_mfma_i32_16x16x64_i8(af[mf], bfr[nf],
                                                              acc[mf][nf], 0, 0, 0);
  }

  conv_epilogue<NFW, MF>(acc, nfw, lane, wave, mbase, yhb, stb, 256);
}

// ---------- small 3x3 conv (b3b/b3c): qstage + whole-B LDS ----------
template <int CI, int KROWP, int COB>
__global__ __launch_bounds__(256, 4) void cstat9q_kernel(
    const u16* __restrict__ yhin, const double* __restrict__ stp,
    const float* __restrict__ gp, const float* __restrict__ bep,
    const char* __restrict__ bp, int nft,
    double* __restrict__ stb, u16* __restrict__ yh) {
  constexpr int CPR = KROWP / 64;
  constexpr int NCH = 3 * CPR;
  constexpr int NFW = COB / 16;
  constexpr int MF = 2;
  constexpr int TILE = 6 * 34 * CI;
  constexpr int BSZ = NCH * NFW * 1024;

  __shared__ __align__(16) char atile[TILE + 64];
  __shared__ __align__(16) char btile[BSZ];
  __shared__ float2 cfl[CI];

  const int tid = threadIdx.x;

  if (tid < CI) {
    double s1d = 0., s2d = 0.;
#pragma unroll
    for (int r = 0; r < NREP; ++r) {
      s1d += stp[r * 256 + 2 * tid];
      s2d += stp[r * 256 + 2 * tid + 1];
    }
    double m = s1d * (1.0 / PTOT);
    double v = s2d * (1.0 / PTOT) - m * m;
    double inv = 1.0 / sqrt(v + 1e-5);
    double c0 = (double)gp[tid] * inv;
    cfl[tid] = make_float2((float)c0, (float)((double)bep[tid] - m * c0));
  }
  for (int s = tid * 16; s < BSZ; s += 4096)
    *(uint4*)&btile[s] = *(const uint4*)(bp + s);
  {
    uint4 z = {0, 0, 0, 0};
    for (int s = tid * 16; s < TILE + 64; s += 4096) *(uint4*)&atile[s] = z;
  }
  __syncthreads();

  const int p0 = blockIdx.x * 128;
  const int n = p0 >> 10, h0 = (p0 & 1023) >> 5;
  for (int task = tid; task < CI * 6; task += 256) {
    int co = task / 6, rr = task - co * 6;
    int irow = h0 - 1 + rr;
    if (irow < 0 || irow > 31) continue;
    const u16* src = yhin + (size_t)co * PTOT + (n << 10) + (irow << 5);
    float2 cc = cfl[co];
    char* dst = &atile[(rr * 34 + 1) * CI + co];
#pragma unroll
    for (int w8 = 0; w8 < 4; ++w8) {
      u16x8 v = *(const u16x8*)(src + w8 * 8);
#pragma unroll
      for (int e = 0; e < 8; ++e) {
        float z = fmaxf(fmaf(bf2f(v[e]), cc.x, cc.y), 0.f);
        dst[(w8 * 8 + e) * CI] = (char)min((int)rintf(z * 128.f), 127);
      }
    }
  }
  __syncthreads();

  const int lane = tid & 63;
  const int wave = tid >> 6;
  const int mbase = blockIdx.x * 128 + wave * 32;

  uint albase[MF];
#pragma unroll
  for (int mf = 0; mf < MF; ++mf) {
    int lp = wave * 32 + mf * 16 + (lane & 15);
    albase[mf] = (uint)((((lp >> 5) + 1) * 34 + 1 + (lp & 31)) * CI);
  }
  const uint klane = (uint)(lane >> 4) * 16u;
  const uint blane = (uint)lane * 16u;

  i32x4 acc[MF][NFW];
#pragma unroll
  for (int i = 0; i < MF; ++i)
#pragma unroll
    for (int j = 0; j < NFW; ++j) acc[i][j] = {0, 0, 0, 0};

#pragma unroll 2
  for (int c = 0; c < NCH; ++c) {
    int rr = c / CPR, o = (c - rr * CPR) * 64;
    uint koff = (uint)((rr - 1) * 34 * CI + o - CI);
    i32x4 af[MF];
#pragma unroll
    for (int mf = 0; mf < MF; ++mf)
      af[mf] = *(const i32x4*)&atile[albase[mf] + koff + klane];
    i32x4 bfr[NFW];
#pragma unroll
    for (int nf = 0; nf < NFW; ++nf)
      bfr[nf] = *(const i32x4*)&btile[(uint)((c * nft + nf) * 1024) + blane];
#pragma unroll
    for (int mf = 0; mf < MF; ++mf)
#pragma unroll
      for (int nf = 0; nf < NFW; ++nf)
        acc[mf][nf] = __builtin_amdgcn_mfma_i32_16x16x64_i8(af[mf], bfr[nf],
                                                            acc[mf][nf], 0, 0, 0);
  }

  conv_epilogue<NFW, MF>(acc, NFW, lane, wave, mbase, yh, stb, 256);
}

// ---------- b2b: qstage + 2x2 wave split (wave = 64 px x 64 co), B global ----------
__global__ __launch_bounds__(256, 3) void cstat9q2_kernel(
    const u16* __restrict__ yhin, const double* __restrict__ stp,
    const float* __restrict__ gp, const float* __restrict__ bep,
    const char* __restrict__ bp, double* __restrict__ stb, u16* __restrict__ yh) {
  constexpr int CI = 96;
  constexpr int CPR = 5;        // KROWP=320
  constexpr int NCH = 15;
  constexpr int MF = 4;
  constexpr int NFW = 4;
  constexpr int TILE = 6 * 34 * CI;

  __shared__ __align__(16) char atile[TILE + 64];
  __shared__ float2 cfl[CI];
  __shared__ float red[4][NFW][16][2];

  const int tid = threadIdx.x;

  if (tid < CI) {
    double s1d = 0., s2d = 0.;
#pragma unroll
    for (int r = 0; r < NREP; ++r) {
      s1d += stp[r * 256 + 2 * tid];
      s2d += stp[r * 256 + 2 * tid + 1];
    }
    double m = s1d * (1.0 / PTOT);
    double v = s2d * (1.0 / PTOT) - m * m;
    double inv = 1.0 / sqrt(v + 1e-5);
    double c0 = (double)gp[tid] * inv;
    cfl[tid] = make_float2((float)c0, (float)((double)bep[tid] - m * c0));
  }
  {
    uint4 z = {0, 0, 0, 0};
    for (int s = tid * 16; s < TILE + 64; s += 4096) *(uint4*)&atile[s] = z;
  }
  __syncthreads();

  const int p0 = blockIdx.x * 128;
  const int n = p0 >> 10, h0 = (p0 & 1023) >> 5;
  for (int task = tid; task < CI * 6; task += 256) {
    int co = task / 6, rr = task - co * 6;
    int irow = h0 - 1 + rr;
    if (irow < 0 || irow > 31) continue;
    const u16* src = yhin + (size_t)co * PTOT + (n << 10) + (irow << 5);
    float2 cc = cfl[co];
    char* dst = &atile[(rr * 34 + 1) * CI + co];
#pragma unroll
    for (int w8 = 0; w8 < 4; ++w8) {
      u16x8 v = *(const u16x8*)(src + w8 * 8);
#pragma unroll
      for (int e = 0; e < 8; ++e) {
        float z = fmaxf(fmaf(bf2f(v[e]), cc.x, cc.y), 0.f);
        dst[(w8 * 8 + e) * CI] = (char)min((int)rintf(z * 128.f), 127);
      }
    }
  }
  __syncthreads();

  const int lane = tid & 63;
  const int wave = tid >> 6;
  const int pg = wave >> 1, cg = wave & 1;

  uint albase[MF];
#pragma unroll
  for (int mf = 0; mf < MF; ++mf) {
    int lp = pg * 64 + mf * 16 + (lane & 15);  // local pixel in [0,128)
    albase[mf] = (uint)((((lp >> 5) + 1) * 34 + 1 + (lp & 31)) * CI);
  }
  const uint klane = (uint)(lane >> 4) * 16u;
  const uint blane = (uint)lane * 16u;

  i32x4 acc[MF][NFW];
#pragma unroll
  for (int i = 0; i < MF; ++i)
#pragma unroll
    for (int j = 0; j < NFW; ++j) acc[i][j] = {0, 0, 0, 0};

#pragma unroll 3
  for (int c = 0; c < NCH; ++c) {
    int rr = c / CPR, o = (c - rr * CPR) * 64;
    uint koff = (uint)((rr - 1) * 34 * CI + o - CI);
    i32x4 af[MF];
#pragma unroll
    for (int mf = 0; mf < MF; ++mf)
      af[mf] = *(const i32x4*)&atile[albase[mf] + koff + klane];
    i32x4 bfr[NFW];
#pragma unroll
    for (int nf = 0; nf < NFW; ++nf)
      bfr[nf] = *(const i32x4*)(bp + ((uint)((c * 8 + cg * 4 + nf) * 1024) + blane));
#pragma unroll
    for (int mf = 0; mf < MF; ++mf)
#pragma unroll
      for (int nf = 0; nf < NFW; ++nf)
        acc[mf][nf] = __builtin_amdgcn_mfma_i32_16x16x64_i8(af[mf], bfr[nf],
                                                            acc[mf][nf], 0, 0, 0);
  }

  // ---- epilogue (2x2): channel = cg*64 + nf*16 + l; pix = p0 + pg*64 + ... ----
  float yv[MF][NFW][4];
#pragma unroll
  for (int mf = 0; mf < MF; ++mf)
#pragma unroll
    for (int nf = 0; nf < NFW; ++nf) {
      int col = cg * 64 + nf * 16 + (lane & 15);
      int pix = p0 + pg * 64 + mf * 16 + ((lane >> 4) << 2);
      u16x4 o;
#pragma unroll
      for (int r = 0; r < 4; ++r) {
        float v = (float)acc[mf][nf][r] * 6.103515625e-05f;
        yv[mf][nf][r] = v;
        o[r] = bf_rne(v);
      }
      *(u16x4*)&yh[(size_t)col * PTOT + pix] = o;
    }

  float s1[NFW], s2[NFW];
#pragma unroll
  for (int nf = 0; nf < NFW; ++nf) { s1[nf] = 0.f; s2[nf] = 0.f; }
#pragma unroll
  for (int mf = 0; mf < MF; ++mf)
#pragma unroll
    for (int nf = 0; nf < NFW; ++nf)
#pragma unroll
      for (int r = 0; r < 4; ++r) {
        float v = yv[mf][nf][r];
        s1[nf] += v;
        s2[nf] += v * v;
      }
#pragma unroll
  for (int m = 16; m <= 32; m <<= 1)
#pragma unroll
    for (int nf = 0; nf < NFW; ++nf) {
      s1[nf] += __shfl_xor(s1[nf], m);
      s2[nf] += __shfl_xor(s2[nf], m);
    }
  if (lane < 16)
#pragma unroll
    for (int nf = 0; nf < NFW; ++nf) {
      red[wave][nf][lane][0] = s1[nf];
      red[wave][nf][lane][1] = s2[nf];
    }
  __syncthreads();
  if (tid < 128) {
    int gch = tid >> 4, l = tid & 15;
    int cg2 = gch >> 2, nf = gch & 3;
    float a = red[cg2][nf][l][0] + red[2 + cg2][nf][l][0];
    float b = red[cg2][nf][l][1] + red[2 + cg2][nf][l][1];
    int rep = blockIdx.x & (NREP - 1);
    atomicAdd(&stb[rep * 256 + 2 * tid], (double)a);
    atomicAdd(&stb[rep * 256 + 2 * tid + 1], (double)b);
  }
}

// ---------- merged BN+ReLU for ALL out-branches -> f32 NCHW out ----------
struct BnPtrs { const float* g[4]; const float* be[4]; };

__global__ __launch_bounds__(256) void bnout_all_kernel(
    const u16* __restrict__ yh, const double* __restrict__ st, BnPtrs bp,
    float* __restrict__ out) {
  int co = blockIdx.y, chunk = blockIdx.x, tid = threadIdx.x;
  int br = (co < 64) ? 0 : (co < 192) ? 1 : (co < 224) ? 2 : 3;
  int lco = co - ((br == 0) ? 0 : (br == 1) ? 64 : (br == 2) ? 192 : 224);
  int yhoff = (br == 0) ? 0 : (br == 1) ? 208 : (br == 2) ? 368 : 176;
  int stoff = (br == 0) ? 0 : (br == 1) ? 2 * 256 * NREP
                         : (br == 2) ? 5 * 256 * NREP : 6 * 256 * NREP;
  const double* stb = st + stoff;
  double s1d = 0., s2d = 0.;
#pragma unroll
  for (int r = 0; r < NREP; ++r) {
    s1d += stb[r * 256 + 2 * lco];
    s2d += stb[r * 256 + 2 * lco + 1];
  }
  double m = s1d * (1.0 / PTOT);
  double v = s2d * (1.0 / PTOT) - m * m;
  double inv = 1.0 / sqrt(v + 1e-5);
  double c0d = (double)bp.g[br][lco] * inv;
  float c0 = (float)c0d;
  float c1 = (float)((double)bp.be[br][lco] - m * c0d);

  int p0 = chunk * 4096 + tid * 16;
  int n = p0 >> 10, hw = p0 & 1023;
  const u16* yp = yh + (size_t)(yhoff + lco) * PTOT + p0;
  float* op = out + (((size_t)(n * 256 + co)) << 10) + hw;
#pragma unroll
  for (int half = 0; half < 2; ++half) {
    u16x8 r = *(const u16x8*)(yp + half * 8);
    f32x4 a, b;
#pragma unroll
    for (int e = 0; e < 4; ++e) {
      a[e] = fmaxf(fmaf(bf2f(r[e]), c0, c1), 0.f);
      b[e] = fmaxf(fmaf(bf2f(r[e + 4]), c0, c1), 0.f);
    }
    *(f32x4*)(op + half * 8) = a;
    *(f32x4*)(op + half * 8 + 4) = b;
  }
}

extern "C" void kernel_launch(void* const* d_in, const int* in_sizes, int n_in,
                              void* d_out, int out_size, void* d_ws, size_t ws_size,
                              hipStream_t stream) {
  const float* x = (const float*)d_in[0];
  float* out = (float*)d_out;
  char* ws = (char*)d_ws;

  // ---- workspace layout (total 155,599,872 B) ----
  if (ws_size < 155599872ull) return;
  char* xq  = ws;                            // [PTOT][192] i8        = 25,165,824 B
  char* xpq = ws + 25165824ull;              // pooled [PTOT][192] i8 = 25,165,824 B
  u16* yh   = (u16*)(ws + 50331648ull);      // [400][PTOT] bf16     = 104,857,600 B
  // yh slices (channel offsets): b1 0, b2a 64, b3a 160, b4 176, b2b 208,
  //                              b3b 336, b3c 368
  char* bpk = ws + 155189248ull;             // packed i8 weights        181,248 B
  double* st = (double*)(ws + 155370496ull); // 7 x NREP x 256 doubles   229,376 B

  hipMemsetAsync(st, 0, 7 * NREP * 256 * 8, stream);

  WPtrs wp;
  const int widx[7] = {1, 5, 9, 13, 17, 21, 25};
  for (int i = 0; i < 7; ++i) wp.p[i] = (const float*)d_in[widx[i]];
  wpack_kernel<<<708, 256, 0, stream>>>(wp, bpk);

  quantx_kernel<<<dim3(16, 3, 128), 256, 0, stream>>>(x, xq);
  pool_kernel<<<6144, 256, 0, stream>>>(xq, xpq);

  double* stB[7];
  for (int b = 0; b < 7; ++b) stB[b] = st + (size_t)b * NREP * 256;

  // ---- merged 1x1 convs: b1 / b2a / b3a / b4 in one launch (B in LDS) ----
  cstat1x1_kernel<<<dim3(1024, 4), 256, 0, stream>>>(xq, xpq, bpk, st, yh);

  // ---- b2b: qstage(b2a) -> 3x3 96->128, 2x2 wave split ----
  cstat9q2_kernel<<<1024, 256, 0, stream>>>(
      yh + (size_t)64 * PTOT, stB[1], (const float*)d_in[7], (const float*)d_in[8],
      bpk + 30720, stB[2], yh + (size_t)208 * PTOT);

  // ---- b3b: qstage(b3a) -> 3x3 16->32, B in LDS ----
  cstat9q_kernel<16, 64, 32><<<1024, 256, 0, stream>>>(
      yh + (size_t)160 * PTOT, stB[3], (const float*)d_in[15], (const float*)d_in[16],
      bpk + 156672, 2, stB[4], yh + (size_t)336 * PTOT);

  // ---- b3c: qstage(b3b) -> 3x3 32->32, B in LDS ----
  cstat9q_kernel<32, 128, 32><<<1024, 256, 0, stream>>>(
      yh + (size_t)336 * PTOT, stB[4], (const float*)d_in[19], (const float*)d_in[20],
      bpk + 162816, 2, stB[5], yh + (size_t)368 * PTOT);

  // ---- single merged BN+ReLU for all 256 output channels ----
  BnPtrs bp;
  bp.g[0] = (const float*)d_in[3];  bp.be[0] = (const float*)d_in[4];   // b1
  bp.g[1] = (const float*)d_in[11]; bp.be[1] = (const float*)d_in[12];  // b2b
  bp.g[2] = (const float*)d_in[23]; bp.be[2] = (const float*)d_in[24];  // b3c
  bp.g[3] = (const float*)d_in[27]; bp.be[3] = (const float*)d_in[28];  // b4
  bnout_all_kernel<<<dim3(32, 256), 256, 0, stream>>>(yh, st, bp, out);
}

// Round 16
// 186.300 us; speedup vs baseline: 1.3396x; 1.0391x over previous
//
#include <hip/hip_runtime.h>

typedef unsigned short u16;
typedef unsigned int u32;
typedef __attribute__((ext_vector_type(4))) int i32x4;
typedef __attribute__((ext_vector_type(4))) float f32x4;
typedef __attribute__((ext_vector_type(4))) u16 u16x4;
typedef __attribute__((ext_vector_type(8))) u16 u16x8;

#define PTOT 131072   // 128 images * 32*32 pixels
#define NREP 16       // stat accumulator replicas (atomic de-contention)

// ---------- helpers ----------
static __device__ __forceinline__ int qi8(float v) {  // round-half-even, clip +-127
  int q = (int)rintf(v * 128.f);
  return max(-127, min(127, q));
}
static __device__ __forceinline__ u16 bf_rne(float v) { // round-nearest-even bf16
  u32 u = __float_as_uint(v);
  u += 0x7fffu + ((u >> 16) & 1u);
  return (u16)(u >> 16);
}
static __device__ __forceinline__ float bf2f(u16 v) {
  return __uint_as_float((u32)v << 16);
}

// ---------- weight quantize + i8 MFMA fragment packing (row-linear K) ----------
struct WPtrs { const float* p[7]; };

__global__ void wpack_kernel(WPtrs wp, char* __restrict__ o) {
  // {byte_off, CIr, KROWP, KH, Co}   (len = NCH*NF*1024)
  static const int S[7][5] = {
      {0,      192, 192, 1, 64},   // b1   NCH=3 NF=4  12288
      {12288,  192, 192, 1, 96},   // b2a  NCH=3 NF=6  18432
      {30720,  96,  320, 3, 128},  // b2b  NCH=15 NF=8 122880
      {153600, 192, 192, 1, 16},   // b3a  NCH=3 NF=1  3072
      {156672, 16,  64,  3, 32},   // b3b  NCH=3 NF=2  6144
      {162816, 32,  128, 3, 32},   // b3c  NCH=6 NF=2  12288
      {175104, 192, 192, 1, 32},   // b4   NCH=3 NF=2  6144
  };
  int idx = blockIdx.x * 256 + threadIdx.x;
  if (idx >= 181248) return;
  int s = 0;
#pragma unroll
  for (int i = 1; i < 7; ++i)
    if (idx >= S[i][0]) s = i;
  int local = idx - S[s][0];
  int CIr = S[s][1], KROWP = S[s][2], KH = S[s][3], Co = S[s][4];
  int j = local & 15, lane = (local >> 4) & 63, f = local >> 10;
  int NF = Co >> 4;
  int c = f / NF, nf = f - c * NF;
  int co = nf * 16 + (lane & 15);
  int k = c * 64 + ((lane >> 4) << 4) + j;
  int r = k / KROWP, kk = k - r * KROWP;
  char val = 0;
  if (kk < 3 * CIr || KH == 1) {
    int kw = (KH == 1) ? 0 : (kk / CIr);
    int ci = (KH == 1) ? kk : (kk - kw * CIr);
    val = (char)qi8(wp.p[s][(((size_t)co * CIr + ci) * KH + r) * KH + kw]);
  }
  o[idx] = val;
}

// ---------- quantize x: NCHW f32 -> NHWC int8 ----------
__global__ __launch_bounds__(256) void quantx_kernel(const float* __restrict__ x,
                                                     char* __restrict__ xq) {
  __shared__ __align__(16) char tile[64][80];
  int n = blockIdx.z, hwb = blockIdx.x * 64, cb = blockIdx.y * 64;
  int lane = threadIdx.x & 63, sub = threadIdx.x >> 6;
#pragma unroll
  for (int i = 0; i < 16; ++i) {
    int c = sub + i * 4;
    float v = x[(((size_t)n * 192 + cb + c) << 10) + hwb + lane];
    tile[lane][c] = (char)qi8(v);
  }
  __syncthreads();
  int t = threadIdx.x, px = t >> 2, c16 = t & 3;
  uint4 v = *(const uint4*)&tile[px][c16 * 16];
  *(uint4*)&xq[(((size_t)n << 10) + hwb + px) * 192 + cb + c16 * 16] = v;
}

// ---------- shared conv epilogue (runtime nfw guard) ----------
template <int NFW, int MF>
static __device__ __forceinline__ void conv_epilogue(
    i32x4 (&acc)[MF][NFW], int nfw, int lane, int wave, int mbase,
    u16* __restrict__ yh, double* __restrict__ stb, int ststride) {
  float yv[MF][NFW][4];
#pragma unroll
  for (int mf = 0; mf < MF; ++mf)
#pragma unroll
    for (int nf = 0; nf < NFW; ++nf)
      if (nf < nfw) {
        int col = nf * 16 + (lane & 15);
        int pix = mbase + mf * 16 + ((lane >> 4) << 2);
        u16x4 o;
#pragma unroll
        for (int r = 0; r < 4; ++r) {
          float v = (float)acc[mf][nf][r] * 6.103515625e-05f;  // 2^-14 (exact)
          yv[mf][nf][r] = v;
          o[r] = bf_rne(v);
        }
        *(u16x4*)&yh[(size_t)col * PTOT + pix] = o;
      }

  float s1[NFW], s2[NFW];
#pragma unroll
  for (int nf = 0; nf < NFW; ++nf) { s1[nf] = 0.f; s2[nf] = 0.f; }
#pragma unroll
  for (int mf = 0; mf < MF; ++mf)
#pragma unroll
    for (int nf = 0; nf < NFW; ++nf)
      if (nf < nfw)
#pragma unroll
        for (int r = 0; r < 4; ++r) {
          float v = yv[mf][nf][r];
          s1[nf] += v;
          s2[nf] += v * v;
        }
#pragma unroll
  for (int m = 16; m <= 32; m <<= 1)
#pragma unroll
    for (int nf = 0; nf < NFW; ++nf) {
      s1[nf] += __shfl_xor(s1[nf], m);
      s2[nf] += __shfl_xor(s2[nf], m);
    }
  __shared__ float red[4][NFW][16][2];
  if (lane < 16)
#pragma unroll
    for (int nf = 0; nf < NFW; ++nf) {
      red[wave][nf][lane][0] = s1[nf];
      red[wave][nf][lane][1] = s2[nf];
    }
  __syncthreads();
  const int t = threadIdx.x;
  if (t < 16 * nfw) {
    int nf = t >> 4, l = t & 15;
    float a = red[0][nf][l][0] + red[1][nf][l][0] + red[2][nf][l][0] + red[3][nf][l][0];
    float b = red[0][nf][l][1] + red[1][nf][l][1] + red[2][nf][l][1] + red[3][nf][l][1];
    int rep = blockIdx.x & (NREP - 1);
    atomicAdd(&stb[rep * ststride + 2 * t], (double)a);
    atomicAdd(&stb[rep * ststride + 2 * t + 1], (double)b);
  }
}

// ---------- merged 1x1 convs {b1,b2a,b3a}: whole-B in LDS ----------
__global__ __launch_bounds__(256, 4) void cstat1x1_kernel(
    const char* __restrict__ xq, const char* __restrict__ bpk,
    double* __restrict__ st, u16* __restrict__ yh) {
  constexpr int NFW = 6;
  constexpr int MF = 2;
  __shared__ __align__(16) char btile[18432];  // max branch B (b2a: 3*6 KB)

  const int b = blockIdx.y;  // uniform
  const int nfw = (b == 0) ? 4 : (b == 1) ? 6 : 1;
  const int bpo = (b == 0) ? 0 : (b == 1) ? 12288 : 153600;
  const int sto = (b == 0) ? 0 : (b == 1) ? 256 * NREP : 3 * 256 * NREP;
  const int yho = (b == 0) ? 0 : (b == 1) ? 64 : 160;
  const char* bp = bpk + bpo;
  double* stb = st + sto;
  u16* yhb = yh + (size_t)yho * PTOT;

  const int tid = threadIdx.x;
  const int bsz = nfw * 3 * 1024;
  for (int s = tid * 16; s < bsz; s += 4096)
    *(uint4*)&btile[s] = *(const uint4*)(bp + s);
  __syncthreads();

  const int lane = tid & 63;
  const int wave = tid >> 6;
  const int mbase = blockIdx.x * 128 + wave * 32;

  uint abase[MF];
#pragma unroll
  for (int mf = 0; mf < MF; ++mf)
    abase[mf] = (uint)(mbase + mf * 16 + (lane & 15)) * 192u;
  const uint klane = (uint)(lane >> 4) * 16u;
  const uint blane = (uint)lane * 16u;

  i32x4 acc[MF][NFW];
#pragma unroll
  for (int i = 0; i < MF; ++i)
#pragma unroll
    for (int j = 0; j < NFW; ++j) acc[i][j] = {0, 0, 0, 0};

#pragma unroll
  for (int c = 0; c < 3; ++c) {
    i32x4 af[MF];
#pragma unroll
    for (int mf = 0; mf < MF; ++mf)
      af[mf] = *(const i32x4*)(xq + (abase[mf] + (uint)c * 64u + klane));
    i32x4 bfr[NFW];
#pragma unroll
    for (int nf = 0; nf < NFW; ++nf)
      if (nf < nfw)
        bfr[nf] = *(const i32x4*)&btile[(uint)((c * nfw + nf) * 1024) + blane];
#pragma unroll
    for (int mf = 0; mf < MF; ++mf)
#pragma unroll
      for (int nf = 0; nf < NFW; ++nf)
        if (nf < nfw)
          acc[mf][nf] = __builtin_amdgcn_mfma_i32_16x16x64_i8(af[mf], bfr[nf],
                                                              acc[mf][nf], 0, 0, 0);
  }

  conv_epilogue<NFW, MF>(acc, nfw, lane, wave, mbase, yhb, stb, 256);
}

// ---------- b4: fused maxpool(xq) -> LDS -> 1x1 conv 192->32 ----------
// Block = 128 px (4 rows, 1 image). Pool computed per-task from L2-hot xq
// (identical clamped 3x3 max as the old pool kernel), written to LDS; conv
// reads A-frags from pooled LDS, B from LDS. No xpq buffer, no pool launch.
__global__ __launch_bounds__(256, 4) void cpool4_kernel(
    const char* __restrict__ xq, const char* __restrict__ bp,
    double* __restrict__ stb, u16* __restrict__ yh) {
  constexpr int NFW = 2;
  constexpr int MF = 2;
  __shared__ __align__(16) char pooled[128 * 192];  // 24,576 B
  __shared__ __align__(16) char btile[6144];

  const int tid = threadIdx.x;
  for (int s = tid * 16; s < 6144; s += 4096)
    *(uint4*)&btile[s] = *(const uint4*)(bp + s);

  const int p0 = blockIdx.x * 128;
  const int n = p0 >> 10, h0 = (p0 & 1023) >> 5;
  for (int task = tid; task < 128 * 12; task += 256) {
    int px = task / 12, c16 = task - px * 12;
    int h = h0 + (px >> 5), w = px & 31;
    int m[16];
#pragma unroll
    for (int j = 0; j < 16; ++j) m[j] = -127;
    for (int dh = -1; dh <= 1; ++dh) {
      int hh = h + dh; if (hh < 0 || hh > 31) continue;
      for (int dw = -1; dw <= 1; ++dw) {
        int ww = w + dw; if (ww < 0 || ww > 31) continue;
        uint4 v = *(const uint4*)&xq[((size_t)((n << 10) + (hh << 5) + ww)) * 192 +
                                     c16 * 16];
        const char* bb = reinterpret_cast<const char*>(&v);
#pragma unroll
        for (int t = 0; t < 16; ++t) {
          int b = (int)bb[t];
          m[t] = b > m[t] ? b : m[t];
        }
      }
    }
    uint4 o;
    char* ob = reinterpret_cast<char*>(&o);
#pragma unroll
    for (int t = 0; t < 16; ++t) ob[t] = (char)m[t];
    *(uint4*)&pooled[px * 192 + c16 * 16] = o;
  }
  __syncthreads();

  const int lane = tid & 63;
  const int wave = tid >> 6;
  const int mbase = blockIdx.x * 128 + wave * 32;

  uint albase[MF];
#pragma unroll
  for (int mf = 0; mf < MF; ++mf)
    albase[mf] = (uint)(wave * 32 + mf * 16 + (lane & 15)) * 192u;
  const uint klane = (uint)(lane >> 4) * 16u;
  const uint blane = (uint)lane * 16u;

  i32x4 acc[MF][NFW];
#pragma unroll
  for (int i = 0; i < MF; ++i)
#pragma unroll
    for (int j = 0; j < NFW; ++j) acc[i][j] = {0, 0, 0, 0};

#pragma unroll
  for (int c = 0; c < 3; ++c) {
    i32x4 af[MF];
#pragma unroll
    for (int mf = 0; mf < MF; ++mf)
      af[mf] = *(const i32x4*)&pooled[albase[mf] + (uint)c * 64u + klane];
    i32x4 bfr[NFW];
#pragma unroll
    for (int nf = 0; nf < NFW; ++nf)
      bfr[nf] = *(const i32x4*)&btile[(uint)((c * NFW + nf) * 1024) + blane];
#pragma unroll
    for (int mf = 0; mf < MF; ++mf)
#pragma unroll
      for (int nf = 0; nf < NFW; ++nf)
        acc[mf][nf] = __builtin_amdgcn_mfma_i32_16x16x64_i8(af[mf], bfr[nf],
                                                            acc[mf][nf], 0, 0, 0);
  }

  conv_epilogue<NFW, MF>(acc, NFW, lane, wave, mbase, yh, stb, 256);
}

// ---------- small 3x3 conv (b3c): qstage + whole-B LDS ----------
template <int CI, int KROWP, int COB>
__global__ __launch_bounds__(256, 4) void cstat9q_kernel(
    const u16* __restrict__ yhin, const double* __restrict__ stp,
    const float* __restrict__ gp, const float* __restrict__ bep,
    const char* __restrict__ bp, int nft,
    double* __restrict__ stb, u16* __restrict__ yh) {
  constexpr int CPR = KROWP / 64;
  constexpr int NCH = 3 * CPR;
  constexpr int NFW = COB / 16;
  constexpr int MF = 2;
  constexpr int TILE = 6 * 34 * CI;
  constexpr int BSZ = NCH * NFW * 1024;

  __shared__ __align__(16) char atile[TILE + 64];
  __shared__ __align__(16) char btile[BSZ];
  __shared__ float2 cfl[CI];

  const int tid = threadIdx.x;

  if (tid < CI) {
    double s1d = 0., s2d = 0.;
#pragma unroll
    for (int r = 0; r < NREP; ++r) {
      s1d += stp[r * 256 + 2 * tid];
      s2d += stp[r * 256 + 2 * tid + 1];
    }
    double m = s1d * (1.0 / PTOT);
    double v = s2d * (1.0 / PTOT) - m * m;
    double inv = 1.0 / sqrt(v + 1e-5);
    double c0 = (double)gp[tid] * inv;
    cfl[tid] = make_float2((float)c0, (float)((double)bep[tid] - m * c0));
  }
  for (int s = tid * 16; s < BSZ; s += 4096)
    *(uint4*)&btile[s] = *(const uint4*)(bp + s);
  {
    uint4 z = {0, 0, 0, 0};
    for (int s = tid * 16; s < TILE + 64; s += 4096) *(uint4*)&atile[s] = z;
  }
  __syncthreads();

  const int p0 = blockIdx.x * 128;
  const int n = p0 >> 10, h0 = (p0 & 1023) >> 5;
  for (int task = tid; task < CI * 6; task += 256) {
    int co = task / 6, rr = task - co * 6;
    int irow = h0 - 1 + rr;
    if (irow < 0 || irow > 31) continue;
    const u16* src = yhin + (size_t)co * PTOT + (n << 10) + (irow << 5);
    float2 cc = cfl[co];
    char* dst = &atile[(rr * 34 + 1) * CI + co];
#pragma unroll
    for (int w8 = 0; w8 < 4; ++w8) {
      u16x8 v = *(const u16x8*)(src + w8 * 8);
#pragma unroll
      for (int e = 0; e < 8; ++e) {
        float z = fmaxf(fmaf(bf2f(v[e]), cc.x, cc.y), 0.f);
        dst[(w8 * 8 + e) * CI] = (char)min((int)rintf(z * 128.f), 127);
      }
    }
  }
  __syncthreads();

  const int lane = tid & 63;
  const int wave = tid >> 6;
  const int mbase = blockIdx.x * 128 + wave * 32;

  uint albase[MF];
#pragma unroll
  for (int mf = 0; mf < MF; ++mf) {
    int lp = wave * 32 + mf * 16 + (lane & 15);
    albase[mf] = (uint)((((lp >> 5) + 1) * 34 + 1 + (lp & 31)) * CI);
  }
  const uint klane = (uint)(lane >> 4) * 16u;
  const uint blane = (uint)lane * 16u;

  i32x4 acc[MF][NFW];
#pragma unroll
  for (int i = 0; i < MF; ++i)
#pragma unroll
    for (int j = 0; j < NFW; ++j) acc[i][j] = {0, 0, 0, 0};

#pragma unroll 2
  for (int c = 0; c < NCH; ++c) {
    int rr = c / CPR, o = (c - rr * CPR) * 64;
    uint koff = (uint)((rr - 1) * 34 * CI + o - CI);
    i32x4 af[MF];
#pragma unroll
    for (int mf = 0; mf < MF; ++mf)
      af[mf] = *(const i32x4*)&atile[albase[mf] + koff + klane];
    i32x4 bfr[NFW];
#pragma unroll
    for (int nf = 0; nf < NFW; ++nf)
      bfr[nf] = *(const i32x4*)&btile[(uint)((c * nft + nf) * 1024) + blane];
#pragma unroll
    for (int mf = 0; mf < MF; ++mf)
#pragma unroll
      for (int nf = 0; nf < NFW; ++nf)
        acc[mf][nf] = __builtin_amdgcn_mfma_i32_16x16x64_i8(af[mf], bfr[nf],
                                                            acc[mf][nf], 0, 0, 0);
  }

  conv_epilogue<NFW, MF>(acc, NFW, lane, wave, mbase, yh, stb, 256);
}

// ---------- merged b2b + b3b (independent; blockIdx.y selects) ----------
struct M2Args {
  const u16* yhin0; const double* stp0; const float* g0; const float* be0;
  const char* bp0; double* stb0; u16* yho0;   // b2b
  const u16* yhin1; const double* stp1; const float* g1; const float* be1;
  const char* bp1; double* stb1; u16* yho1;   // b3b
};

__global__ __launch_bounds__(256, 3) void cstat9m_kernel(M2Args A) {
  __shared__ __align__(16) char atile[6 * 34 * 96 + 64];  // b2b size; b3b uses prefix
  __shared__ __align__(16) char btile[6144];               // b3b only
  __shared__ float2 cfl[96];
  __shared__ float redm[4][4][16][2];                      // b2b custom epilogue

  const int tid = threadIdx.x;

  if (blockIdx.y == 0) {
    // ===== b2b: qstage(b2a) -> 3x3 96->128, 2x2 wave split, B global =====
    constexpr int CI = 96;
    constexpr int CPR = 5;
    constexpr int NCH = 15;
    constexpr int MF = 4;
    constexpr int NFW = 4;
    constexpr int TILE = 6 * 34 * CI;

    if (tid < CI) {
      double s1d = 0., s2d = 0.;
#pragma unroll
      for (int r = 0; r < NREP; ++r) {
        s1d += A.stp0[r * 256 + 2 * tid];
        s2d += A.stp0[r * 256 + 2 * tid + 1];
      }
      double m = s1d * (1.0 / PTOT);
      double v = s2d * (1.0 / PTOT) - m * m;
      double inv = 1.0 / sqrt(v + 1e-5);
      double c0 = (double)A.g0[tid] * inv;
      cfl[tid] = make_float2((float)c0, (float)((double)A.be0[tid] - m * c0));
    }
    {
      uint4 z = {0, 0, 0, 0};
      for (int s = tid * 16; s < TILE + 64; s += 4096) *(uint4*)&atile[s] = z;
    }
    __syncthreads();

    const int p0 = blockIdx.x * 128;
    const int n = p0 >> 10, h0 = (p0 & 1023) >> 5;
    for (int task = tid; task < CI * 6; task += 256) {
      int co = task / 6, rr = task - co * 6;
      int irow = h0 - 1 + rr;
      if (irow < 0 || irow > 31) continue;
      const u16* src = A.yhin0 + (size_t)co * PTOT + (n << 10) + (irow << 5);
      float2 cc = cfl[co];
      char* dst = &atile[(rr * 34 + 1) * CI + co];
#pragma unroll
      for (int w8 = 0; w8 < 4; ++w8) {
        u16x8 v = *(const u16x8*)(src + w8 * 8);
#pragma unroll
        for (int e = 0; e < 8; ++e) {
          float z = fmaxf(fmaf(bf2f(v[e]), cc.x, cc.y), 0.f);
          dst[(w8 * 8 + e) * CI] = (char)min((int)rintf(z * 128.f), 127);
        }
      }
    }
    __syncthreads();

    const int lane = tid & 63;
    const int wave = tid >> 6;
    const int pg = wave >> 1, cg = wave & 1;

    uint albase[MF];
#pragma unroll
    for (int mf = 0; mf < MF; ++mf) {
      int lp = pg * 64 + mf * 16 + (lane & 15);
      albase[mf] = (uint)((((lp >> 5) + 1) * 34 + 1 + (lp & 31)) * CI);
    }
    const uint klane = (uint)(lane >> 4) * 16u;
    const uint blane = (uint)lane * 16u;

    i32x4 acc[MF][NFW];
#pragma unroll
    for (int i = 0; i < MF; ++i)
#pragma unroll
      for (int j = 0; j < NFW; ++j) acc[i][j] = {0, 0, 0, 0};

#pragma unroll 3
    for (int c = 0; c < NCH; ++c) {
      int rr = c / CPR, o = (c - rr * CPR) * 64;
      uint koff = (uint)((rr - 1) * 34 * CI + o - CI);
      i32x4 af[MF];
#pragma unroll
      for (int mf = 0; mf < MF; ++mf)
        af[mf] = *(const i32x4*)&atile[albase[mf] + koff + klane];
      i32x4 bfr[NFW];
#pragma unroll
      for (int nf = 0; nf < NFW; ++nf)
        bfr[nf] = *(const i32x4*)(A.bp0 +
                                  ((uint)((c * 8 + cg * 4 + nf) * 1024) + blane));
#pragma unroll
      for (int mf = 0; mf < MF; ++mf)
#pragma unroll
        for (int nf = 0; nf < NFW; ++nf)
          acc[mf][nf] = __builtin_amdgcn_mfma_i32_16x16x64_i8(af[mf], bfr[nf],
                                                              acc[mf][nf], 0, 0, 0);
    }

    float yv[MF][NFW][4];
#pragma unroll
    for (int mf = 0; mf < MF; ++mf)
#pragma unroll
      for (int nf = 0; nf < NFW; ++nf) {
        int col = cg * 64 + nf * 16 + (lane & 15);
        int pix = p0 + pg * 64 + mf * 16 + ((lane >> 4) << 2);
        u16x4 o;
#pragma unroll
        for (int r = 0; r < 4; ++r) {
          float v = (float)acc[mf][nf][r] * 6.103515625e-05f;
          yv[mf][nf][r] = v;
          o[r] = bf_rne(v);
        }
        *(u16x4*)&A.yho0[(size_t)col * PTOT + pix] = o;
      }

    float s1[NFW], s2[NFW];
#pragma unroll
    for (int nf = 0; nf < NFW; ++nf) { s1[nf] = 0.f; s2[nf] = 0.f; }
#pragma unroll
    for (int mf = 0; mf < MF; ++mf)
#pragma unroll
      for (int nf = 0; nf < NFW; ++nf)
#pragma unroll
        for (int r = 0; r < 4; ++r) {
          float v = yv[mf][nf][r];
          s1[nf] += v;
          s2[nf] += v * v;
        }
#pragma unroll
    for (int m = 16; m <= 32; m <<= 1)
#pragma unroll
      for (int nf = 0; nf < NFW; ++nf) {
        s1[nf] += __shfl_xor(s1[nf], m);
        s2[nf] += __shfl_xor(s2[nf], m);
      }
    if (lane < 16)
#pragma unroll
      for (int nf = 0; nf < NFW; ++nf) {
        redm[wave][nf][lane][0] = s1[nf];
        redm[wave][nf][lane][1] = s2[nf];
      }
    __syncthreads();
    if (tid < 128) {
      int gch = tid >> 4, l = tid & 15;
      int cg2 = gch >> 2, nf = gch & 3;
      float a = redm[cg2][nf][l][0] + redm[2 + cg2][nf][l][0];
      float b = redm[cg2][nf][l][1] + redm[2 + cg2][nf][l][1];
      int rep = blockIdx.x & (NREP - 1);
      atomicAdd(&A.stb0[rep * 256 + 2 * tid], (double)a);
      atomicAdd(&A.stb0[rep * 256 + 2 * tid + 1], (double)b);
    }
  } else {
    // ===== b3b: qstage(b3a) -> 3x3 16->32, B in LDS =====
    constexpr int CI = 16;
    constexpr int CPR = 1;
    constexpr int NCH = 3;
    constexpr int MF = 2;
    constexpr int NFW = 2;
    constexpr int TILE = 6 * 34 * CI;

    if (tid < CI) {
      double s1d = 0., s2d = 0.;
#pragma unroll
      for (int r = 0; r < NREP; ++r) {
        s1d += A.stp1[r * 256 + 2 * tid];
        s2d += A.stp1[r * 256 + 2 * tid + 1];
      }
      double m = s1d * (1.0 / PTOT);
      double v = s2d * (1.0 / PTOT) - m * m;
      double inv = 1.0 / sqrt(v + 1e-5);
      double c0 = (double)A.g1[tid] * inv;
      cfl[tid] = make_float2((float)c0, (float)((double)A.be1[tid] - m * c0));
    }
    for (int s = tid * 16; s < 6144; s += 4096)
      *(uint4*)&btile[s] = *(const uint4*)(A.bp1 + s);
    {
      uint4 z = {0, 0, 0, 0};
      for (int s = tid * 16; s < TILE + 64; s += 4096) *(uint4*)&atile[s] = z;
    }
    __syncthreads();

    const int p0 = blockIdx.x * 128;
    const int n = p0 >> 10, h0 = (p0 & 1023) >> 5;
    for (int task = tid; task < CI * 6; task += 256) {
      int co = task / 6, rr = task - co * 6;
      int irow = h0 - 1 + rr;
      if (irow < 0 || irow > 31) continue;
      const u16* src = A.yhin1 + (size_t)co * PTOT + (n << 10) + (irow << 5);
      float2 cc = cfl[co];
      char* dst = &atile[(rr * 34 + 1) * CI + co];
#pragma unroll
      for (int w8 = 0; w8 < 4; ++w8) {
        u16x8 v = *(const u16x8*)(src + w8 * 8);
#pragma unroll
        for (int e = 0; e < 8; ++e) {
          float z = fmaxf(fmaf(bf2f(v[e]), cc.x, cc.y), 0.f);
          dst[(w8 * 8 + e) * CI] = (char)min((int)rintf(z * 128.f), 127);
        }
      }
    }
    __syncthreads();

    const int lane = tid & 63;
    const int wave = tid >> 6;
    const int mbase = blockIdx.x * 128 + wave * 32;

    uint albase[MF];
#pragma unroll
    for (int mf = 0; mf < MF; ++mf) {
      int lp = wave * 32 + mf * 16 + (lane & 15);
      albase[mf] = (uint)((((lp >> 5) + 1) * 34 + 1 + (lp & 31)) * CI);
    }
    const uint klane = (uint)(lane >> 4) * 16u;
    const uint blane = (uint)lane * 16u;

    i32x4 acc[MF][NFW];
#pragma unroll
    for (int i = 0; i < MF; ++i)
#pragma unroll
      for (int j = 0; j < NFW; ++j) acc[i][j] = {0, 0, 0, 0};

#pragma unroll
    for (int c = 0; c < NCH; ++c) {
      int rr = c / CPR, o = (c - rr * CPR) * 64;
      uint koff = (uint)((rr - 1) * 34 * CI + o - CI);
      i32x4 af[MF];
#pragma unroll
      for (int mf = 0; mf < MF; ++mf)
        af[mf] = *(const i32x4*)&atile[albase[mf] + koff + klane];
      i32x4 bfr[NFW];
#pragma unroll
      for (int nf = 0; nf < NFW; ++nf)
        bfr[nf] = *(const i32x4*)&btile[(uint)((c * 2 + nf) * 1024) + blane];
#pragma unroll
      for (int mf = 0; mf < MF; ++mf)
#pragma unroll
        for (int nf = 0; nf < NFW; ++nf)
          acc[mf][nf] = __builtin_amdgcn_mfma_i32_16x16x64_i8(af[mf], bfr[nf],
                                                              acc[mf][nf], 0, 0, 0);
    }

    conv_epilogue<NFW, MF>(acc, NFW, lane, wave, mbase, A.yho1, A.stb1, 256);
  }
}

// ---------- merged BN+ReLU for ALL out-branches -> f32 NCHW out ----------
struct BnPtrs { const float* g[4]; const float* be[4]; };

__global__ __launch_bounds__(256) void bnout_all_kernel(
    const u16* __restrict__ yh, const double* __restrict__ st, BnPtrs bp,
    float* __restrict__ out) {
  int co = blockIdx.y, chunk = blockIdx.x, tid = threadIdx.x;
  int br = (co < 64) ? 0 : (co < 192) ? 1 : (co < 224) ? 2 : 3;
  int lco = co - ((br == 0) ? 0 : (br == 1) ? 64 : (br == 2) ? 192 : 224);
  int yhoff = (br == 0) ? 0 : (br == 1) ? 208 : (br == 2) ? 368 : 176;
  int stoff = (br == 0) ? 0 : (br == 1) ? 2 * 256 * NREP
                         : (br == 2) ? 5 * 256 * NREP : 6 * 256 * NREP;
  const double* stb = st + stoff;
  double s1d = 0., s2d = 0.;
#pragma unroll
  for (int r = 0; r < NREP; ++r) {
    s1d += stb[r * 256 + 2 * lco];
    s2d += stb[r * 256 + 2 * lco + 1];
  }
  double m = s1d * (1.0 / PTOT);
  double v = s2d * (1.0 / PTOT) - m * m;
  double inv = 1.0 / sqrt(v + 1e-5);
  double c0d = (double)bp.g[br][lco] * inv;
  float c0 = (float)c0d;
  float c1 = (float)((double)bp.be[br][lco] - m * c0d);

  int p0 = chunk * 4096 + tid * 16;
  int n = p0 >> 10, hw = p0 & 1023;
  const u16* yp = yh + (size_t)(yhoff + lco) * PTOT + p0;
  float* op = out + (((size_t)(n * 256 + co)) << 10) + hw;
#pragma unroll
  for (int half = 0; half < 2; ++half) {
    u16x8 r = *(const u16x8*)(yp + half * 8);
    f32x4 a, b;
#pragma unroll
    for (int e = 0; e < 4; ++e) {
      a[e] = fmaxf(fmaf(bf2f(r[e]), c0, c1), 0.f);
      b[e] = fmaxf(fmaf(bf2f(r[e + 4]), c0, c1), 0.f);
    }
    *(f32x4*)(op + half * 8) = a;
    *(f32x4*)(op + half * 8 + 4) = b;
  }
}

extern "C" void kernel_launch(void* const* d_in, const int* in_sizes, int n_in,
                              void* d_out, int out_size, void* d_ws, size_t ws_size,
                              hipStream_t stream) {
  const float* x = (const float*)d_in[0];
  float* out = (float*)d_out;
  char* ws = (char*)d_ws;

  // ---- workspace layout (total 155,599,872 B) ----
  if (ws_size < 155599872ull) return;
  char* xq  = ws;                            // [PTOT][192] i8        = 25,165,824 B
  u16* yh   = (u16*)(ws + 50331648ull);      // [400][PTOT] bf16     = 104,857,600 B
  // yh slices (channel offsets): b1 0, b2a 64, b3a 160, b4 176, b2b 208,
  //                              b3b 336, b3c 368
  char* bpk = ws + 155189248ull;             // packed i8 weights        181,248 B
  double* st = (double*)(ws + 155370496ull); // 7 x NREP x 256 doubles   229,376 B

  hipMemsetAsync(st, 0, 7 * NREP * 256 * 8, stream);

  WPtrs wp;
  const int widx[7] = {1, 5, 9, 13, 17, 21, 25};
  for (int i = 0; i < 7; ++i) wp.p[i] = (const float*)d_in[widx[i]];
  wpack_kernel<<<708, 256, 0, stream>>>(wp, bpk);

  quantx_kernel<<<dim3(16, 3, 128), 256, 0, stream>>>(x, xq);

  double* stB[7];
  for (int b = 0; b < 7; ++b) stB[b] = st + (size_t)b * NREP * 256;

  // ---- b4: fused pool + 1x1 conv (xq -> pooled LDS -> conv) ----
  cpool4_kernel<<<1024, 256, 0, stream>>>(xq, bpk + 175104, stB[6],
                                          yh + (size_t)176 * PTOT);

  // ---- merged 1x1 convs: b1 / b2a / b3a ----
  cstat1x1_kernel<<<dim3(1024, 3), 256, 0, stream>>>(xq, bpk, st, yh);

  // ---- merged b2b + b3b (independent, co-dispatched) ----
  M2Args A;
  A.yhin0 = yh + (size_t)64 * PTOT;  A.stp0 = stB[1];
  A.g0 = (const float*)d_in[7];      A.be0 = (const float*)d_in[8];
  A.bp0 = bpk + 30720;               A.stb0 = stB[2];
  A.yho0 = yh + (size_t)208 * PTOT;
  A.yhin1 = yh + (size_t)160 * PTOT; A.stp1 = stB[3];
  A.g1 = (const float*)d_in[15];     A.be1 = (const float*)d_in[16];
  A.bp1 = bpk + 156672;              A.stb1 = stB[4];
  A.yho1 = yh + (size_t)336 * PTOT;
  cstat9m_kernel<<<dim3(1024, 2), 256, 0, stream>>>(A);

  // ---- b3c: qstage(b3b) -> 3x3 32->32, B in LDS ----
  cstat9q_kernel<32, 128, 32><<<1024, 256, 0, stream>>>(
      yh + (size_t)336 * PTOT, stB[4], (const float*)d_in[19], (const float*)d_in[20],
      bpk + 162816, 2, stB[5], yh + (size_t)368 * PTOT);

  // ---- single merged BN+ReLU for all 256 output channels ----
  BnPtrs bp;
  bp.g[0] = (const float*)d_in[3];  bp.be[0] = (const float*)d_in[4];   // b1
  bp.g[1] = (const float*)d_in[11]; bp.be[1] = (const float*)d_in[12];  // b2b
  bp.g[2] = (const float*)d_in[23]; bp.be[2] = (const float*)d_in[24];  // b3c
  bp.g[3] = (const float*)d_in[27]; bp.be[3] = (const float*)d_in[28];  // b4
  bnout_all_kernel<<<dim3(32, 256), 256, 0, stream>>>(yh, st, bp, out);
}